// Round 5
// baseline (756.975 us; speedup 1.0000x reference)
//
#include <hip/hip_runtime.h>

#define EPSV 1e-5f

static inline int cdiv(int a, int b) { return (a + b - 1) / b; }

__global__ void zero_kernel(float* __restrict__ p, int n) {
  int i = blockIdx.x * blockDim.x + threadIdx.x;
  if (i < n) p[i] = 0.f;
}

// ---- cooperative stage of W cout-slice into LDS (padded k-stride) ----
template<int CI, int CO, int COB, int WSTRIDE>
__device__ inline void stage_weights(const float* __restrict__ w, float* sW, int cb) {
  constexpr int Q = COB / 4;
  for (int idx = threadIdx.x; idx < 27 * CI * Q; idx += 256) {
    int k = idx / (CI * Q);
    int r = idx - k * (CI * Q);
    int ci = r / Q;
    int oq = r - ci * Q;
    float4 v = *(const float4*)(w + ((long)k * CI + ci) * CO + cb + oq * 4);
    *(float4*)(&sW[k * WSTRIDE + ci * COB + oq * 4]) = v;
  }
}

template<int COT>
__device__ inline void fma_block(const float* wk, int cj, float fc, float (&acc)[COT]) {
  const float4* wr = (const float4*)(wk + cj);
#pragma unroll
  for (int o4 = 0; o4 < COT / 4; ++o4) {
    float4 wv = wr[o4];
    acc[o4 * 4 + 0] = fmaf(fc, wv.x, acc[o4 * 4 + 0]);
    acc[o4 * 4 + 1] = fmaf(fc, wv.y, acc[o4 * 4 + 1]);
    acc[o4 * 4 + 2] = fmaf(fc, wv.z, acc[o4 * 4 + 2]);
    acc[o4 * 4 + 3] = fmaf(fc, wv.w, acc[o4 * 4 + 3]);
  }
}

// ================= dense (full-27) conv, fused BN-relu gather, ROWS rows/thread ================
template<int CI, int CO, int COB, int COT, int ROWS>
__global__ __launch_bounds__(256) void conv_full_f(
    const float* __restrict__ f1, const float* __restrict__ st1,
    const float* __restrict__ g1, const float* __restrict__ b1, float inv_n1,
    const int* __restrict__ nbr, const float* __restrict__ w,
    float* __restrict__ y, float* __restrict__ stats, int nout) {
  constexpr int TPR = COB / COT;
  constexpr int CHUNK = (CI < 16) ? CI : 16;
  constexpr int NCH = CI / CHUNK;
  constexpr int C4 = CHUNK / 4;
  constexpr int WSTRIDE = CI * COB + 4;
  __shared__ __align__(16) float sW[27 * WSTRIDE];
  __shared__ __align__(16) float sBN[2 * CI];
  __shared__ float s_red[2 * COB];
  const int cb = blockIdx.y * COB;

  stage_weights<CI, CO, COB, WSTRIDE>(w, sW, cb);
  if ((int)threadIdx.x < CI) {
    int o = threadIdx.x;
    float mu = st1[o] * inv_n1;
    float var = st1[64 + o] * inv_n1 - mu * mu;
    float a = g1[o] * rsqrtf(var + EPSV);
    sBN[o] = a;
    sBN[CI + o] = fmaf(-mu, a, b1[o]);
  }
  for (int i = threadIdx.x; i < 2 * COB; i += 256) s_red[i] = 0.f;
  __syncthreads();

  const long t = (long)blockIdx.x * 256 + threadIdx.x;
  const long tr = t / TPR;
  const int part = (int)(t % TPR);
  const int ob = part * COT;
  const int lane = threadIdx.x & 63;

  int nrow[ROWS];
  bool rok[ROWS];
#pragma unroll
  for (int r = 0; r < ROWS; ++r) {
    nrow[r] = (int)(tr * ROWS + r);
    rok[r] = nrow[r] < nout;
  }

  float acc[ROWS][COT];
#pragma unroll
  for (int r = 0; r < ROWS; ++r)
#pragma unroll
    for (int o = 0; o < COT; ++o) acc[r][o] = 0.f;

#pragma unroll 1
  for (int ch = 0; ch < NCH; ++ch) {
    const int chb = ch * CHUNK;
    float4 rA[C4], rC[C4];
#pragma unroll
    for (int c = 0; c < C4; ++c) {
      rA[c] = *(const float4*)(&sBN[chb + c * 4]);
      rC[c] = *(const float4*)(&sBN[CI + chb + c * 4]);
    }
    int idxA[ROWS], idxB[ROWS];
    float4 buf[ROWS][C4];
#pragma unroll
    for (int r = 0; r < ROWS; ++r) {
      idxA[r] = rok[r] ? nbr[(long)nrow[r] * 27 + 0] : -1;
      idxB[r] = rok[r] ? nbr[(long)nrow[r] * 27 + 1] : -1;
    }
#pragma unroll
    for (int r = 0; r < ROWS; ++r) {
      const float4* fr = (const float4*)(f1 + (long)max(idxA[r], 0) * CI + chb);
#pragma unroll
      for (int c = 0; c < C4; ++c) buf[r][c] = fr[c];
    }
#pragma unroll 1
    for (int k = 0; k < 27; ++k) {
      float4 nbuf[ROWS][C4];
      if (k < 26) {
#pragma unroll
        for (int r = 0; r < ROWS; ++r) {
          const float4* fr = (const float4*)(f1 + (long)max(idxB[r], 0) * CI + chb);
#pragma unroll
          for (int c = 0; c < C4; ++c) nbuf[r][c] = fr[c];
        }
      }
      int idxC[ROWS];
#pragma unroll
      for (int r = 0; r < ROWS; ++r)
        idxC[r] = (k + 2 < 27 && rok[r]) ? nbr[(long)nrow[r] * 27 + k + 2] : -1;

      const float* wk = &sW[k * WSTRIDE + chb * COB + ob];
#pragma unroll
      for (int r = 0; r < ROWS; ++r) {
        if (idxA[r] >= 0) {
#pragma unroll
          for (int c = 0; c < C4; ++c) {
            float4 raw = buf[r][c];
            float4 v;
            v.x = fmaxf(fmaf(raw.x, rA[c].x, rC[c].x), 0.f);
            v.y = fmaxf(fmaf(raw.y, rA[c].y, rC[c].y), 0.f);
            v.z = fmaxf(fmaf(raw.z, rA[c].z, rC[c].z), 0.f);
            v.w = fmaxf(fmaf(raw.w, rA[c].w, rC[c].w), 0.f);
            fma_block<COT>(wk, (c * 4 + 0) * COB, v.x, acc[r]);
            fma_block<COT>(wk, (c * 4 + 1) * COB, v.y, acc[r]);
            fma_block<COT>(wk, (c * 4 + 2) * COB, v.z, acc[r]);
            fma_block<COT>(wk, (c * 4 + 3) * COB, v.w, acc[r]);
          }
        }
      }
#pragma unroll
      for (int r = 0; r < ROWS; ++r) {
        idxA[r] = idxB[r];
        idxB[r] = idxC[r];
#pragma unroll
        for (int c = 0; c < C4; ++c) buf[r][c] = nbuf[r][c];
      }
    }
  }

#pragma unroll
  for (int r = 0; r < ROWS; ++r) {
    if (rok[r]) {
      float* yr = y + (long)nrow[r] * CO + cb + ob;
#pragma unroll
      for (int o4 = 0; o4 < COT / 4; ++o4)
        *(float4*)(yr + o4 * 4) =
            make_float4(acc[r][4 * o4], acc[r][4 * o4 + 1], acc[r][4 * o4 + 2], acc[r][4 * o4 + 3]);
    }
  }
#pragma unroll
  for (int o = 0; o < COT; ++o) {
    float v = 0.f, q = 0.f;
#pragma unroll
    for (int r = 0; r < ROWS; ++r) {
      v += acc[r][o];
      q = fmaf(acc[r][o], acc[r][o], q);
    }
#pragma unroll
    for (int off = 32; off >= TPR; off >>= 1) {
      v += __shfl_xor(v, off);
      q += __shfl_xor(q, off);
    }
    if (lane < TPR) {
      atomicAdd(&s_red[lane * COT + o], v);
      atomicAdd(&s_red[COB + lane * COT + o], q);
    }
  }
  __syncthreads();
  if ((int)threadIdx.x < COB) {
    atomicAdd(&stats[cb + threadIdx.x], s_red[threadIdx.x]);
    atomicAdd(&stats[64 + cb + threadIdx.x], s_red[COB + threadIdx.x]);
  }
}

// ================= compacted conv (sparse tables), fused BN-relu gather =================
// NSRC: 0 = raw input, 1 = relu(bn(f1)), 2 = relu(bn(f1)) + relu(bn(f2))
template<int CI, int CO, int COB, int COT, int NSRC>
__global__ __launch_bounds__(256) void conv_compact_f(
    const float* __restrict__ f1, const float* __restrict__ st1,
    const float* __restrict__ g1, const float* __restrict__ b1, float inv_n1,
    const float* __restrict__ f2, const float* __restrict__ st2,
    const float* __restrict__ g2, const float* __restrict__ b2, float inv_n2,
    const int* __restrict__ nbr, const float* __restrict__ w,
    float* __restrict__ y, float* __restrict__ stats, int nout) {
  constexpr int TPR = COB / COT;
  constexpr int CHUNK = (CI < 16) ? CI : 16;
  constexpr int NCH = CI / CHUNK;
  constexpr int C4 = CHUNK / 4;
  constexpr int WSTRIDE = CI * COB + 4;
  constexpr int NBN = (NSRC > 0) ? NSRC : 1;
  __shared__ __align__(16) float sW[27 * WSTRIDE];
  __shared__ __align__(16) float sBN[NBN * 2 * CI];
  __shared__ float s_red[2 * COB];
  const int cb = blockIdx.y * COB;

  stage_weights<CI, CO, COB, WSTRIDE>(w, sW, cb);
  if constexpr (NSRC >= 1) {
    if ((int)threadIdx.x < CI) {
      int o = threadIdx.x;
      float mu = st1[o] * inv_n1;
      float var = st1[64 + o] * inv_n1 - mu * mu;
      float a = g1[o] * rsqrtf(var + EPSV);
      sBN[o] = a;
      sBN[CI + o] = fmaf(-mu, a, b1[o]);
    }
  }
  if constexpr (NSRC == 2) {
    if ((int)threadIdx.x >= 128 && (int)threadIdx.x < 128 + CI) {
      int o = threadIdx.x - 128;
      float mu = st2[o] * inv_n2;
      float var = st2[64 + o] * inv_n2 - mu * mu;
      float a = g2[o] * rsqrtf(var + EPSV);
      sBN[2 * CI + o] = a;
      sBN[3 * CI + o] = fmaf(-mu, a, b2[o]);
    }
  }
  for (int i = threadIdx.x; i < 2 * COB; i += 256) s_red[i] = 0.f;
  __syncthreads();

  const long t = (long)blockIdx.x * 256 + threadIdx.x;
  const int n = (int)(t / TPR);
  const int part = (int)(t % TPR);
  const int ob = part * COT;
  const int lane = threadIdx.x & 63;

  float acc[COT];
#pragma unroll
  for (int o = 0; o < COT; ++o) acc[o] = 0.f;

  unsigned mask0 = 0;
  int nbv[27];
  if (n < nout) {
    const int* nb = nbr + (long)n * 27;
#pragma unroll
    for (int k = 0; k < 27; ++k) {
      nbv[k] = nb[k];
      mask0 |= (nbv[k] >= 0 ? 1u : 0u) << k;
    }
  }

#pragma unroll 1
  for (int ch = 0; ch < NCH; ++ch) {
    const int chb = ch * CHUNK;
    float4 rA1[C4], rC1[C4], rA2[C4], rC2[C4];
    if constexpr (NSRC >= 1) {
#pragma unroll
      for (int c = 0; c < C4; ++c) {
        rA1[c] = *(const float4*)(&sBN[chb + c * 4]);
        rC1[c] = *(const float4*)(&sBN[CI + chb + c * 4]);
      }
    }
    if constexpr (NSRC == 2) {
#pragma unroll
      for (int c = 0; c < C4; ++c) {
        rA2[c] = *(const float4*)(&sBN[2 * CI + chb + c * 4]);
        rC2[c] = *(const float4*)(&sBN[3 * CI + chb + c * 4]);
      }
    }

    if constexpr (NSRC == 2) {
      unsigned m = mask0;
#pragma unroll 1
      while (m) {
        int k = __builtin_ctz(m);
        m &= m - 1;
        long idx = nbv[k];
        const float4* p1 = (const float4*)(f1 + idx * CI + chb);
        const float4* p2 = (const float4*)(f2 + idx * CI + chb);
        float4 v1[C4], v2[C4];
#pragma unroll
        for (int c = 0; c < C4; ++c) v1[c] = p1[c];
#pragma unroll
        for (int c = 0; c < C4; ++c) v2[c] = p2[c];
        const float* wk = &sW[k * WSTRIDE + chb * COB + ob];
#pragma unroll
        for (int c = 0; c < C4; ++c) {
          float4 v;
          v.x = fmaxf(fmaf(v1[c].x, rA1[c].x, rC1[c].x), 0.f) + fmaxf(fmaf(v2[c].x, rA2[c].x, rC2[c].x), 0.f);
          v.y = fmaxf(fmaf(v1[c].y, rA1[c].y, rC1[c].y), 0.f) + fmaxf(fmaf(v2[c].y, rA2[c].y, rC2[c].y), 0.f);
          v.z = fmaxf(fmaf(v1[c].z, rA1[c].z, rC1[c].z), 0.f) + fmaxf(fmaf(v2[c].z, rA2[c].z, rC2[c].z), 0.f);
          v.w = fmaxf(fmaf(v1[c].w, rA1[c].w, rC1[c].w), 0.f) + fmaxf(fmaf(v2[c].w, rA2[c].w, rC2[c].w), 0.f);
          fma_block<COT>(wk, (c * 4 + 0) * COB, v.x, acc);
          fma_block<COT>(wk, (c * 4 + 1) * COB, v.y, acc);
          fma_block<COT>(wk, (c * 4 + 2) * COB, v.z, acc);
          fma_block<COT>(wk, (c * 4 + 3) * COB, v.w, acc);
        }
      }
    } else {
      unsigned m = mask0;
      int k = -1;
      float4 buf[C4], nbuf[C4];
      if (m) {
        k = __builtin_ctz(m);
        m &= m - 1;
        const float4* fr = (const float4*)(f1 + (long)nbv[k] * CI + chb);
#pragma unroll
        for (int c = 0; c < C4; ++c) buf[c] = fr[c];
      }
#pragma unroll 1
      while (k >= 0) {
        int k2 = -1;
        if (m) {
          k2 = __builtin_ctz(m);
          m &= m - 1;
          const float4* fr = (const float4*)(f1 + (long)nbv[k2] * CI + chb);
#pragma unroll
          for (int c = 0; c < C4; ++c) nbuf[c] = fr[c];
        }
        const float* wk = &sW[k * WSTRIDE + chb * COB + ob];
#pragma unroll
        for (int c = 0; c < C4; ++c) {
          float4 v = buf[c];
          if constexpr (NSRC == 1) {
            v.x = fmaxf(fmaf(v.x, rA1[c].x, rC1[c].x), 0.f);
            v.y = fmaxf(fmaf(v.y, rA1[c].y, rC1[c].y), 0.f);
            v.z = fmaxf(fmaf(v.z, rA1[c].z, rC1[c].z), 0.f);
            v.w = fmaxf(fmaf(v.w, rA1[c].w, rC1[c].w), 0.f);
          }
          fma_block<COT>(wk, (c * 4 + 0) * COB, v.x, acc);
          fma_block<COT>(wk, (c * 4 + 1) * COB, v.y, acc);
          fma_block<COT>(wk, (c * 4 + 2) * COB, v.z, acc);
          fma_block<COT>(wk, (c * 4 + 3) * COB, v.w, acc);
        }
        k = k2;
#pragma unroll
        for (int c = 0; c < C4; ++c) buf[c] = nbuf[c];
      }
    }
  }

  if (n < nout) {
    float* yr = y + (long)n * CO + cb + ob;
#pragma unroll
    for (int o4 = 0; o4 < COT / 4; ++o4)
      *(float4*)(yr + o4 * 4) =
          make_float4(acc[4 * o4], acc[4 * o4 + 1], acc[4 * o4 + 2], acc[4 * o4 + 3]);
  }
#pragma unroll
  for (int o = 0; o < COT; ++o) {
    float v = acc[o];
    float q = v * v;
#pragma unroll
    for (int off = 32; off >= TPR; off >>= 1) {
      v += __shfl_xor(v, off);
      q += __shfl_xor(q, off);
    }
    if (lane < TPR) {
      atomicAdd(&s_red[lane * COT + o], v);
      atomicAdd(&s_red[COB + lane * COT + o], q);
    }
  }
  __syncthreads();
  if ((int)threadIdx.x < COB) {
    atomicAdd(&stats[cb + threadIdx.x], s_red[threadIdx.x]);
    atomicAdd(&stats[64 + cb + threadIdx.x], s_red[COB + threadIdx.x]);
  }
}

// ================= fused tail: x0 = relu(bn(y0)) + relu(bn(y9)); out0 = x0 @ lin_w.T ========
__global__ __launch_bounds__(256) void tail_kernel(
    const float* __restrict__ y0, const float* __restrict__ st0,
    const float* __restrict__ g0, const float* __restrict__ b0,
    const float* __restrict__ st9, const float* __restrict__ g9,
    const float* __restrict__ b9, float inv_n,
    const float* __restrict__ lin_w,
    float* y9out,  // reads y9, then overwritten with linear output (same buffer)
    float* __restrict__ x0, int n0) {
  __shared__ float swl[64];
  __shared__ float sbn[32];
  if (threadIdx.x < 64) swl[threadIdx.x] = lin_w[threadIdx.x];
  if (threadIdx.x < 8) {
    int o = threadIdx.x;
    float mu = st0[o] * inv_n;
    float var = st0[64 + o] * inv_n - mu * mu;
    float a = g0[o] * rsqrtf(var + EPSV);
    sbn[o] = a;
    sbn[8 + o] = fmaf(-mu, a, b0[o]);
  } else if (threadIdx.x < 16) {
    int o = threadIdx.x - 8;
    float mu = st9[o] * inv_n;
    float var = st9[64 + o] * inv_n - mu * mu;
    float a = g9[o] * rsqrtf(var + EPSV);
    sbn[16 + o] = a;
    sbn[24 + o] = fmaf(-mu, a, b9[o]);
  }
  __syncthreads();
  int n = blockIdx.x * 256 + threadIdx.x;
  if (n >= n0) return;
  const float4* p0 = (const float4*)(y0 + (long)n * 8);
  float4 a0 = p0[0], a1 = p0[1];
  const float4* p9 = (const float4*)(y9out + (long)n * 8);
  float4 c0 = p9[0], c1 = p9[1];
  float r0[8] = {a0.x, a0.y, a0.z, a0.w, a1.x, a1.y, a1.z, a1.w};
  float r9[8] = {c0.x, c0.y, c0.z, c0.w, c1.x, c1.y, c1.z, c1.w};
  float xv[8];
#pragma unroll
  for (int c = 0; c < 8; ++c)
    xv[c] = fmaxf(fmaf(r0[c], sbn[c], sbn[8 + c]), 0.f) +
            fmaxf(fmaf(r9[c], sbn[16 + c], sbn[24 + c]), 0.f);
  *(float4*)(x0 + (long)n * 8) = make_float4(xv[0], xv[1], xv[2], xv[3]);
  *(float4*)(x0 + (long)n * 8 + 4) = make_float4(xv[4], xv[5], xv[6], xv[7]);
  float ov[8];
#pragma unroll
  for (int j = 0; j < 8; ++j) {
    float s = 0.f;
#pragma unroll
    for (int c = 0; c < 8; ++c) s = fmaf(xv[c], swl[j * 8 + c], s);
    ov[j] = s;
  }
  *(float4*)(y9out + (long)n * 8) = make_float4(ov[0], ov[1], ov[2], ov[3]);
  *(float4*)(y9out + (long)n * 8 + 4) = make_float4(ov[4], ov[5], ov[6], ov[7]);
}

extern "C" void kernel_launch(void* const* d_in, const int* in_sizes, int n_in,
                              void* d_out, int out_size, void* d_ws, size_t ws_size,
                              hipStream_t stream) {
  const float* feats   = (const float*)d_in[0];
  const int* nbr0      = (const int*)d_in[1];
  const int* nbr_d01   = (const int*)d_in[2];
  const int* nbr1      = (const int*)d_in[3];
  const int* nbr_d12   = (const int*)d_in[4];
  const int* nbr2      = (const int*)d_in[5];
  const int* nbr_d23   = (const int*)d_in[6];
  const int* nbr3      = (const int*)d_in[7];
  const int* nbr_u32   = (const int*)d_in[8];
  const int* nbr_u21   = (const int*)d_in[9];
  const int* nbr_u10   = (const int*)d_in[10];
  const float* w[10];
  const float* g[10];
  const float* b[10];
  for (int i = 0; i < 10; ++i) {
    w[i] = (const float*)d_in[11 + 3 * i];
    g[i] = (const float*)d_in[12 + 3 * i];
    b[i] = (const float*)d_in[13 + 3 * i];
  }
  const float* lin_w = (const float*)d_in[41];

  const int N0 = in_sizes[0] / 16;
  const int N1 = in_sizes[2] / 27;
  const int N2 = in_sizes[4] / 27;
  const int N3 = in_sizes[6] / 27;
  const float i0 = 1.f / N0, i1 = 1.f / N1, i2 = 1.f / N2, i3 = 1.f / N3;

  // ---- workspace arena (floats). Raw conv outputs y_i persist until last consumer.
  float* ws    = (float*)d_ws;
  float* stats = ws;                          // 10 x 128
  float* y0    = stats + 1280;                // N0*8   (until tail)
  float* y2    = y0 + (size_t)N0 * 8;         // N1*16  (until conv9)
  float* y4    = y2 + (size_t)N1 * 16;        // N2*32  (until conv8)
  float* y8    = y4 + (size_t)N2 * 32;        // N1*16  (until conv9)
  float* yB    = y8 + (size_t)N1 * 16;        // N1*16 region: y1 -> y3 -> y7
  float* y5    = yB + (size_t)N1 * 16;        // N3*64
  float* y6    = y5 + (size_t)N3 * 64;        // N3*64
  float* y9    = (float*)d_out;               // N0*8 staged in linear-output region
  float* x0    = (float*)d_out + (size_t)N0 * 8;

  float* s0 = stats + 0 * 128; float* s1 = stats + 1 * 128; float* s2 = stats + 2 * 128;
  float* s3 = stats + 3 * 128; float* s4 = stats + 4 * 128; float* s5 = stats + 5 * 128;
  float* s6 = stats + 6 * 128; float* s7 = stats + 7 * 128; float* s8 = stats + 8 * 128;
  float* s9 = stats + 9 * 128;

  auto blk = [](int nout, int rows, int tpr) { return cdiv(cdiv(nout, rows) * tpr, 256); };

  zero_kernel<<<cdiv(1280, 256), 256, 0, stream>>>(stats, 1280);

  // conv0: 16->8 @ N0, raw input, sparse -> compact NSRC=0
  conv_compact_f<16, 8, 8, 8, 0><<<dim3(blk(N0, 1, 1), 1), 256, 0, stream>>>(
      feats, nullptr, nullptr, nullptr, 0.f, nullptr, nullptr, nullptr, nullptr, 0.f,
      nbr0, w[0], y0, s0, N0);

  // conv1: 8->16 down to N1, src relu(bn(y0;s0)) -> compact NSRC=1
  conv_compact_f<8, 16, 16, 16, 1><<<dim3(blk(N1, 1, 1), 1), 256, 0, stream>>>(
      y0, s0, g[0], b[0], i0, nullptr, nullptr, nullptr, nullptr, 0.f,
      nbr_d01, w[1], yB, s1, N1);

  // conv2: 16->16 @ N1, src relu(bn(y1;s1)) -> full ROWS=2
  conv_full_f<16, 16, 16, 8, 2><<<dim3(blk(N1, 2, 2), 1), 256, 0, stream>>>(
      yB, s1, g[1], b[1], i1, nbr1, w[2], y2, s2, N1);

  // conv3: 16->32 down to N2, src relu(bn(y2;s2)) -> full ROWS=2, COB=8, y=4
  conv_full_f<16, 32, 8, 4, 2><<<dim3(blk(N2, 2, 2), 4), 256, 0, stream>>>(
      y2, s2, g[2], b[2], i1, nbr_d12, w[3], yB, s3, N2);

  // conv4: 32->32 @ N2, src relu(bn(y3;s3)) -> full ROWS=2, COB=8, y=4
  conv_full_f<32, 32, 8, 4, 2><<<dim3(blk(N2, 2, 2), 4), 256, 0, stream>>>(
      yB, s3, g[3], b[3], i2, nbr2, w[4], y4, s4, N2);

  // conv5: 32->64 down to N3, src relu(bn(y4;s4)) -> full ROWS=1, COB=8, y=8
  conv_full_f<32, 64, 8, 4, 1><<<dim3(blk(N3, 1, 2), 8), 256, 0, stream>>>(
      y4, s4, g[4], b[4], i2, nbr_d23, w[5], y5, s5, N3);

  // conv6: 64->64 @ N3, src relu(bn(y5;s5)) -> full ROWS=1, COB=8, y=8
  conv_full_f<64, 64, 8, 4, 1><<<dim3(blk(N3, 1, 2), 8), 256, 0, stream>>>(
      y5, s5, g[5], b[5], i3, nbr3, w[6], y6, s6, N3);

  // conv7: 64->32 up to N2, src relu(bn(y6;s6)), parity-sparse -> compact NSRC=1, COB=8, y=4
  conv_compact_f<64, 32, 8, 8, 1><<<dim3(blk(N2, 1, 1), 4), 256, 0, stream>>>(
      y6, s6, g[6], b[6], i3, nullptr, nullptr, nullptr, nullptr, 0.f,
      nbr_u32, w[7], yB, s7, N2);

  // conv8: 32->16 up to N1, src relu(bn(y4;s4)) + relu(bn(y7;s7)) -> compact NSRC=2, y=2
  conv_compact_f<32, 16, 8, 8, 2><<<dim3(blk(N1, 1, 1), 2), 256, 0, stream>>>(
      y4, s4, g[4], b[4], i2, yB, s7, g[7], b[7], i2,
      nbr_u21, w[8], y8, s8, N1);

  // conv9: 16->8 up to N0, src relu(bn(y2;s2)) + relu(bn(y8;s8)) -> compact NSRC=2
  conv_compact_f<16, 8, 8, 8, 2><<<dim3(blk(N0, 1, 1), 1), 256, 0, stream>>>(
      y2, s2, g[2], b[2], i1, y8, s8, g[8], b[8], i1,
      nbr_u10, w[9], y9, s9, N0);

  // tail: x0 = relu(bn(y0;s0)) + relu(bn(y9;s9)); out0 = x0 @ lin_w.T (in place over y9)
  tail_kernel<<<cdiv(N0, 256), 256, 0, stream>>>(
      y0, s0, g[0], b[0], s9, g[9], b[9], i0, lin_w, y9, x0, N0);
}

// Round 6
// 711.003 us; speedup vs baseline: 1.0647x; 1.0647x over previous
//
#include <hip/hip_runtime.h>

#define EPSV 1e-5f

static inline int cdiv(int a, int b) { return (a + b - 1) / b; }

__global__ void zero_kernel(float* __restrict__ p, int n) {
  int i = blockIdx.x * blockDim.x + threadIdx.x;
  if (i < n) p[i] = 0.f;
}

// ---- cooperative stage of W cout-slice into LDS (padded k-stride) ----
template<int CI, int CO, int COB, int WSTRIDE>
__device__ inline void stage_weights(const float* __restrict__ w, float* sW, int cb) {
  constexpr int Q = COB / 4;
  for (int idx = threadIdx.x; idx < 27 * CI * Q; idx += 256) {
    int k = idx / (CI * Q);
    int r = idx - k * (CI * Q);
    int ci = r / Q;
    int oq = r - ci * Q;
    float4 v = *(const float4*)(w + ((long)k * CI + ci) * CO + cb + oq * 4);
    *(float4*)(&sW[k * WSTRIDE + ci * COB + oq * 4]) = v;
  }
}

template<int COT>
__device__ inline void fma_block(const float* wk, int cj, float fc, float (&acc)[COT]) {
  const float4* wr = (const float4*)(wk + cj);
#pragma unroll
  for (int o4 = 0; o4 < COT / 4; ++o4) {
    float4 wv = wr[o4];
    acc[o4 * 4 + 0] = fmaf(fc, wv.x, acc[o4 * 4 + 0]);
    acc[o4 * 4 + 1] = fmaf(fc, wv.y, acc[o4 * 4 + 1]);
    acc[o4 * 4 + 2] = fmaf(fc, wv.z, acc[o4 * 4 + 2]);
    acc[o4 * 4 + 3] = fmaf(fc, wv.w, acc[o4 * 4 + 3]);
  }
}

// ---- shared epilogue: y store + BN stats reduce ----
template<int CO, int COB, int COT, int ROWS>
__device__ inline void conv_epilogue(float (&acc)[ROWS][COT], const int* nrow, const bool* rok,
                                     float* __restrict__ y, float* s_red,
                                     float* __restrict__ stats, int cb, int ob, int lane) {
  constexpr int TPR = COB / COT;
#pragma unroll
  for (int r = 0; r < ROWS; ++r) {
    if (rok[r]) {
      float* yr = y + (long)nrow[r] * CO + cb + ob;
#pragma unroll
      for (int o4 = 0; o4 < COT / 4; ++o4)
        *(float4*)(yr + o4 * 4) =
            make_float4(acc[r][4 * o4], acc[r][4 * o4 + 1], acc[r][4 * o4 + 2], acc[r][4 * o4 + 3]);
    }
  }
#pragma unroll
  for (int o = 0; o < COT; ++o) {
    float v = 0.f, q = 0.f;
#pragma unroll
    for (int r = 0; r < ROWS; ++r) {
      v += acc[r][o];
      q = fmaf(acc[r][o], acc[r][o], q);
    }
#pragma unroll
    for (int off = 32; off >= TPR; off >>= 1) {
      v += __shfl_xor(v, off);
      q += __shfl_xor(q, off);
    }
    if (lane < TPR) {
      atomicAdd(&s_red[lane * COT + o], v);
      atomicAdd(&s_red[COB + lane * COT + o], q);
    }
  }
  __syncthreads();
  if ((int)threadIdx.x < COB) {
    atomicAdd(&stats[cb + threadIdx.x], s_red[threadIdx.x]);
    atomicAdd(&stats[64 + cb + threadIdx.x], s_red[COB + threadIdx.x]);
  }
}

// ================= dense conv: depth-2 pipelined k-loop, weights in LDS =================
template<int CI, int CO, int COT, int COB, int ROWS>
__global__ __launch_bounds__(256) void conv_full(
    const float* __restrict__ f, const int* __restrict__ nbr,
    const float* __restrict__ w, float* __restrict__ y,
    float* __restrict__ stats, int nout) {
  constexpr int TPR = COB / COT;
  constexpr int CHUNK = (CI < 16) ? CI : 16;
  constexpr int NCH = CI / CHUNK;
  constexpr int C4 = CHUNK / 4;
  constexpr int WSTRIDE = CI * COB + 4;
  __shared__ __align__(16) float sW[27 * WSTRIDE];
  __shared__ float s_red[2 * COB];
  const int cb = blockIdx.y * COB;

  stage_weights<CI, CO, COB, WSTRIDE>(w, sW, cb);
  for (int i = threadIdx.x; i < 2 * COB; i += 256) s_red[i] = 0.f;
  __syncthreads();

  const long t = (long)blockIdx.x * 256 + threadIdx.x;
  const long tr = t / TPR;
  const int part = (int)(t % TPR);
  const int ob = part * COT;
  const int lane = threadIdx.x & 63;

  int nrow[ROWS];
  bool rok[ROWS];
  const int* nb[ROWS];
#pragma unroll
  for (int r = 0; r < ROWS; ++r) {
    nrow[r] = (int)(tr * ROWS + r);
    rok[r] = nrow[r] < nout;
    nb[r] = nbr + (long)(rok[r] ? nrow[r] : 0) * 27;
  }

  float acc[ROWS][COT];
#pragma unroll
  for (int r = 0; r < ROWS; ++r)
#pragma unroll
    for (int o = 0; o < COT; ++o) acc[r][o] = 0.f;

#pragma unroll 1
  for (int ch = 0; ch < NCH; ++ch) {
    const int chb = ch * CHUNK;
    // idx queue: iq[q][r] = idx(k+q) at iteration k
    int iq[4][ROWS];
#pragma unroll
    for (int q = 0; q < 4; ++q)
#pragma unroll
      for (int r = 0; r < ROWS; ++r) iq[q][r] = rok[r] ? nb[r][q] : -1;

    float4 buf[3][ROWS][C4];
    // preload features for k=0,1
#pragma unroll
    for (int q = 0; q < 2; ++q)
#pragma unroll
      for (int r = 0; r < ROWS; ++r) {
        const float4* fr = (const float4*)(f + (long)max(iq[q][r], 0) * CI + chb);
#pragma unroll
        for (int c = 0; c < C4; ++c) buf[q][r][c] = fr[c];
      }

#pragma unroll 3
    for (int k = 0; k < 27; ++k) {
      const int kb = k % 3;
      if (k + 2 < 27) {
        const int kn = (k + 2) % 3;
#pragma unroll
        for (int r = 0; r < ROWS; ++r) {
          const float4* fr = (const float4*)(f + (long)max(iq[2][r], 0) * CI + chb);
#pragma unroll
          for (int c = 0; c < C4; ++c) buf[kn][r][c] = fr[c];
        }
      }
      const float* wk = &sW[k * WSTRIDE + chb * COB + ob];
#pragma unroll
      for (int r = 0; r < ROWS; ++r) {
        if (iq[0][r] >= 0) {
#pragma unroll
          for (int c = 0; c < C4; ++c) {
            float4 v = buf[kb][r][c];
            fma_block<COT>(wk, (c * 4 + 0) * COB, v.x, acc[r]);
            fma_block<COT>(wk, (c * 4 + 1) * COB, v.y, acc[r]);
            fma_block<COT>(wk, (c * 4 + 2) * COB, v.z, acc[r]);
            fma_block<COT>(wk, (c * 4 + 3) * COB, v.w, acc[r]);
          }
        }
      }
#pragma unroll
      for (int r = 0; r < ROWS; ++r) {
        iq[0][r] = iq[1][r];
        iq[1][r] = iq[2][r];
        iq[2][r] = iq[3][r];
        iq[3][r] = (k + 4 < 27 && rok[r]) ? nb[r][k + 4] : -1;
      }
    }
  }
  conv_epilogue<CO, COB, COT, ROWS>(acc, nrow, rok, y, s_red, stats, cb, ob, lane);
}

// ================= compacted conv: pair-unrolled depth-2 pipeline ===================
template<int CI, int CO, int COT, int COB>
__global__ __launch_bounds__(256) void conv_compact(
    const float* __restrict__ f, const int* __restrict__ nbr,
    const float* __restrict__ w, float* __restrict__ y,
    float* __restrict__ stats, int nout) {
  constexpr int TPR = COB / COT;
  constexpr int CHUNK = (CI < 16) ? CI : 16;
  constexpr int NCH = CI / CHUNK;
  constexpr int C4 = CHUNK / 4;
  constexpr int WSTRIDE = CI * COB + 4;
  __shared__ __align__(16) float sW[27 * WSTRIDE];
  __shared__ float s_red[2 * COB];
  const int cb = blockIdx.y * COB;

  stage_weights<CI, CO, COB, WSTRIDE>(w, sW, cb);
  for (int i = threadIdx.x; i < 2 * COB; i += 256) s_red[i] = 0.f;
  __syncthreads();

  const long t = (long)blockIdx.x * 256 + threadIdx.x;
  const int n = (int)(t / TPR);
  const int part = (int)(t % TPR);
  const int ob = part * COT;
  const int lane = threadIdx.x & 63;

  float accs[1][COT];
#pragma unroll
  for (int o = 0; o < COT; ++o) accs[0][o] = 0.f;
  float (&acc)[COT] = accs[0];

  unsigned mask0 = 0;
  int nbv[27];
  if (n < nout) {
    const int* nbp = nbr + (long)n * 27;
#pragma unroll
    for (int k = 0; k < 27; ++k) {
      nbv[k] = nbp[k];
      mask0 |= (nbv[k] >= 0 ? 1u : 0u) << k;
    }
  }

#pragma unroll 1
  for (int ch = 0; ch < NCH; ++ch) {
    const int chb = ch * CHUNK;
    unsigned m = mask0;
    int k0 = -1, k1 = -1;
    float4 b0[C4], b1[C4];
    if (m) {
      k0 = __builtin_ctz(m); m &= m - 1;
      const float4* fr = (const float4*)(f + (long)nbv[k0] * CI + chb);
#pragma unroll
      for (int c = 0; c < C4; ++c) b0[c] = fr[c];
    }
    if (m) {
      k1 = __builtin_ctz(m); m &= m - 1;
      const float4* fr = (const float4*)(f + (long)nbv[k1] * CI + chb);
#pragma unroll
      for (int c = 0; c < C4; ++c) b1[c] = fr[c];
    }
#pragma unroll 1
    while (k0 >= 0) {
      int k2 = -1, k3 = -1;
      float4 n0[C4], n1[C4];
      if (m) {
        k2 = __builtin_ctz(m); m &= m - 1;
        const float4* fr = (const float4*)(f + (long)nbv[k2] * CI + chb);
#pragma unroll
        for (int c = 0; c < C4; ++c) n0[c] = fr[c];
      }
      if (m) {
        k3 = __builtin_ctz(m); m &= m - 1;
        const float4* fr = (const float4*)(f + (long)nbv[k3] * CI + chb);
#pragma unroll
        for (int c = 0; c < C4; ++c) n1[c] = fr[c];
      }
      {
        const float* wk = &sW[k0 * WSTRIDE + chb * COB + ob];
#pragma unroll
        for (int c = 0; c < C4; ++c) {
          float4 v = b0[c];
          fma_block<COT>(wk, (c * 4 + 0) * COB, v.x, acc);
          fma_block<COT>(wk, (c * 4 + 1) * COB, v.y, acc);
          fma_block<COT>(wk, (c * 4 + 2) * COB, v.z, acc);
          fma_block<COT>(wk, (c * 4 + 3) * COB, v.w, acc);
        }
      }
      if (k1 >= 0) {
        const float* wk = &sW[k1 * WSTRIDE + chb * COB + ob];
#pragma unroll
        for (int c = 0; c < C4; ++c) {
          float4 v = b1[c];
          fma_block<COT>(wk, (c * 4 + 0) * COB, v.x, acc);
          fma_block<COT>(wk, (c * 4 + 1) * COB, v.y, acc);
          fma_block<COT>(wk, (c * 4 + 2) * COB, v.z, acc);
          fma_block<COT>(wk, (c * 4 + 3) * COB, v.w, acc);
        }
      }
      k0 = k2; k1 = k3;
#pragma unroll
      for (int c = 0; c < C4; ++c) { b0[c] = n0[c]; b1[c] = n1[c]; }
    }
  }

  int nrow[1] = {n};
  bool rok[1] = {n < nout};
  conv_epilogue<CO, COB, COT, 1>(accs, nrow, rok, y, s_red, stats, cb, ob, lane);
}

// ---- vectorized BN+ReLU (+optional skip), in-place safe ----
template<int CO>
__global__ __launch_bounds__(256) void bn_relu_kernel(
    const float* __restrict__ y, const float* __restrict__ stats,
    const float* __restrict__ g, const float* __restrict__ b,
    const float* __restrict__ skip, float* __restrict__ out, int nout, float inv_n) {
  long i4 = (long)blockIdx.x * 256 + threadIdx.x;
  long total4 = (long)nout * CO / 4;
  if (i4 >= total4) return;
  int o = (int)((i4 * 4) % CO);
  float a[4], c[4];
#pragma unroll
  for (int j = 0; j < 4; ++j) {
    float mu = stats[o + j] * inv_n;
    float var = stats[64 + o + j] * inv_n - mu * mu;
    a[j] = g[o + j] * rsqrtf(var + EPSV);
    c[j] = fmaf(-mu, a[j], b[o + j]);
  }
  float4 v = ((const float4*)y)[i4];
  float4 r;
  r.x = fmaxf(fmaf(v.x, a[0], c[0]), 0.f);
  r.y = fmaxf(fmaf(v.y, a[1], c[1]), 0.f);
  r.z = fmaxf(fmaf(v.z, a[2], c[2]), 0.f);
  r.w = fmaxf(fmaf(v.w, a[3], c[3]), 0.f);
  if (skip) {
    float4 s = ((const float4*)skip)[i4];
    r.x += s.x; r.y += s.y; r.z += s.z; r.w += s.w;
  }
  ((float4*)out)[i4] = r;
}

// ---- fused tail: x0 = c0f + relu(bn(y9)); out0 = x0 @ lin_w.T (in place over y9) ----
__global__ __launch_bounds__(256) void tail_kernel(
    const float* __restrict__ c0f, const float* __restrict__ st9,
    const float* __restrict__ g9, const float* __restrict__ b9, float inv_n,
    const float* __restrict__ lin_w, float* y9out, float* __restrict__ x0, int n0) {
  __shared__ float swl[64];
  __shared__ float sbn[16];
  if (threadIdx.x < 64) swl[threadIdx.x] = lin_w[threadIdx.x];
  if (threadIdx.x < 8) {
    int o = threadIdx.x;
    float mu = st9[o] * inv_n;
    float var = st9[64 + o] * inv_n - mu * mu;
    float a = g9[o] * rsqrtf(var + EPSV);
    sbn[o] = a;
    sbn[8 + o] = fmaf(-mu, a, b9[o]);
  }
  __syncthreads();
  int n = blockIdx.x * 256 + threadIdx.x;
  if (n >= n0) return;
  const float4* ps = (const float4*)(c0f + (long)n * 8);
  float4 s0 = ps[0], s1 = ps[1];
  const float4* pr = (const float4*)(y9out + (long)n * 8);
  float4 r0 = pr[0], r1 = pr[1];
  float rs[8] = {s0.x, s0.y, s0.z, s0.w, s1.x, s1.y, s1.z, s1.w};
  float rr[8] = {r0.x, r0.y, r0.z, r0.w, r1.x, r1.y, r1.z, r1.w};
  float xv[8];
#pragma unroll
  for (int cidx = 0; cidx < 8; ++cidx)
    xv[cidx] = rs[cidx] + fmaxf(fmaf(rr[cidx], sbn[cidx], sbn[8 + cidx]), 0.f);
  *(float4*)(x0 + (long)n * 8) = make_float4(xv[0], xv[1], xv[2], xv[3]);
  *(float4*)(x0 + (long)n * 8 + 4) = make_float4(xv[4], xv[5], xv[6], xv[7]);
  float ov[8];
#pragma unroll
  for (int j = 0; j < 8; ++j) {
    float s = 0.f;
#pragma unroll
    for (int cidx = 0; cidx < 8; ++cidx) s = fmaf(xv[cidx], swl[j * 8 + cidx], s);
    ov[j] = s;
  }
  *(float4*)(y9out + (long)n * 8) = make_float4(ov[0], ov[1], ov[2], ov[3]);
  *(float4*)(y9out + (long)n * 8 + 4) = make_float4(ov[4], ov[5], ov[6], ov[7]);
}

extern "C" void kernel_launch(void* const* d_in, const int* in_sizes, int n_in,
                              void* d_out, int out_size, void* d_ws, size_t ws_size,
                              hipStream_t stream) {
  const float* feats   = (const float*)d_in[0];
  const int* nbr0      = (const int*)d_in[1];
  const int* nbr_d01   = (const int*)d_in[2];
  const int* nbr1      = (const int*)d_in[3];
  const int* nbr_d12   = (const int*)d_in[4];
  const int* nbr2      = (const int*)d_in[5];
  const int* nbr_d23   = (const int*)d_in[6];
  const int* nbr3      = (const int*)d_in[7];
  const int* nbr_u32   = (const int*)d_in[8];
  const int* nbr_u21   = (const int*)d_in[9];
  const int* nbr_u10   = (const int*)d_in[10];
  const float* w[10];
  const float* g[10];
  const float* b[10];
  for (int i = 0; i < 10; ++i) {
    w[i] = (const float*)d_in[11 + 3 * i];
    g[i] = (const float*)d_in[12 + 3 * i];
    b[i] = (const float*)d_in[13 + 3 * i];
  }
  const float* lin_w = (const float*)d_in[41];

  const int N0 = in_sizes[0] / 16;
  const int N1 = in_sizes[2] / 27;
  const int N2 = in_sizes[4] / 27;
  const int N3 = in_sizes[6] / 27;
  const float i0 = 1.f / N0, i1 = 1.f / N1, i2 = 1.f / N2, i3 = 1.f / N3;

  // ---- workspace layout (floats) ----
  float* ws    = (float*)d_ws;
  float* stats = ws;                       // 10 slots x 128
  float* c0f   = stats + 1280;             // N0*8
  float* t1    = c0f + (size_t)N0 * 8;     // N1*16
  float* c2f   = t1 + (size_t)N1 * 16;     // N1*16
  float* t2    = c2f + (size_t)N1 * 16;    // N2*32
  float* c4f   = t2 + (size_t)N2 * 32;     // N2*32
  float* t3    = c4f + (size_t)N2 * 32;    // N3*64
  float* t4    = t3 + (size_t)N3 * 64;     // N3*64
  float* t5    = t2;                       // reuse
  float* t6    = t1;                       // reuse
  float* y9    = (float*)d_out;            // conv9 raw staged in linear-out region
  float* x0    = (float*)d_out + (size_t)N0 * 8;

  float* s[10];
  for (int i = 0; i < 10; ++i) s[i] = stats + i * 128;

  auto blk = [](int nout, int rows, int tpr) { return cdiv(cdiv(nout, rows) * tpr, 256); };
  auto bgrid = [](int nout, int co) { return cdiv(nout * co / 4, 256); };

  zero_kernel<<<cdiv(1280, 256), 256, 0, stream>>>(stats, 1280);

  // conv0: 16->8 @ N0 (sparse level 0)
  conv_compact<16, 8, 8, 8><<<dim3(blk(N0, 1, 1), 1), 256, 0, stream>>>(
      feats, nbr0, w[0], c0f, s[0], N0);
  bn_relu_kernel<8><<<bgrid(N0, 8), 256, 0, stream>>>(c0f, s[0], g[0], b[0], nullptr, c0f, N0, i0);

  // conv1: 8->16 down to N1 (gathers sparse level 0)
  conv_compact<8, 16, 16, 16><<<dim3(blk(N1, 1, 1), 1), 256, 0, stream>>>(
      c0f, nbr_d01, w[1], t1, s[1], N1);
  bn_relu_kernel<16><<<bgrid(N1, 16), 256, 0, stream>>>(t1, s[1], g[1], b[1], nullptr, t1, N1, i1);

  // conv2: 16->16 @ N1 (dense-ish)
  conv_full<16, 16, 8, 16, 2><<<dim3(blk(N1, 2, 2), 1), 256, 0, stream>>>(
      t1, nbr1, w[2], c2f, s[2], N1);
  bn_relu_kernel<16><<<bgrid(N1, 16), 256, 0, stream>>>(c2f, s[2], g[2], b[2], nullptr, c2f, N1, i1);

  // conv3: 16->32 down to N2
  conv_full<16, 32, 4, 8, 2><<<dim3(blk(N2, 2, 2), 4), 256, 0, stream>>>(
      c2f, nbr_d12, w[3], t2, s[3], N2);
  bn_relu_kernel<32><<<bgrid(N2, 32), 256, 0, stream>>>(t2, s[3], g[3], b[3], nullptr, t2, N2, i2);

  // conv4: 32->32 @ N2
  conv_full<32, 32, 4, 8, 2><<<dim3(blk(N2, 2, 2), 4), 256, 0, stream>>>(
      t2, nbr2, w[4], c4f, s[4], N2);
  bn_relu_kernel<32><<<bgrid(N2, 32), 256, 0, stream>>>(c4f, s[4], g[4], b[4], nullptr, c4f, N2, i2);

  // conv5: 32->64 down to N3
  conv_full<32, 64, 4, 8, 1><<<dim3(blk(N3, 1, 2), 8), 256, 0, stream>>>(
      c4f, nbr_d23, w[5], t3, s[5], N3);
  bn_relu_kernel<64><<<bgrid(N3, 64), 256, 0, stream>>>(t3, s[5], g[5], b[5], nullptr, t3, N3, i3);

  // conv6: 64->64 @ N3
  conv_full<64, 64, 4, 8, 1><<<dim3(blk(N3, 1, 2), 8), 256, 0, stream>>>(
      t3, nbr3, w[6], t4, s[6], N3);
  bn_relu_kernel<64><<<bgrid(N3, 64), 256, 0, stream>>>(t4, s[6], g[6], b[6], nullptr, t4, N3, i3);

  // conv7: 64->32 up to N2 (parity-sparse); then x2 = c4f + relu(bn(y7))
  conv_compact<64, 32, 8, 8><<<dim3(blk(N2, 1, 1), 4), 256, 0, stream>>>(
      t4, nbr_u32, w[7], t5, s[7], N2);
  bn_relu_kernel<32><<<bgrid(N2, 32), 256, 0, stream>>>(t5, s[7], g[7], b[7], c4f, t5, N2, i2);

  // conv8: 32->16 up to N1 (parity-sparse); then x1 = c2f + relu(bn(y8))
  conv_compact<32, 16, 8, 8><<<dim3(blk(N1, 1, 1), 2), 256, 0, stream>>>(
      t5, nbr_u21, w[8], t6, s[8], N1);
  bn_relu_kernel<16><<<bgrid(N1, 16), 256, 0, stream>>>(t6, s[8], g[8], b[8], c2f, t6, N1, i1);

  // conv9: 16->8 up to N0 (parity-sparse); raw y9 staged in out region
  conv_compact<16, 8, 8, 8><<<dim3(blk(N0, 1, 1), 1), 256, 0, stream>>>(
      t6, nbr_u10, w[9], y9, s[9], N0);

  // tail: x0 = c0f + relu(bn(y9)); out0 = x0 @ lin_w.T
  tail_kernel<<<cdiv(N0, 256), 256, 0, stream>>>(
      c0f, s[9], g[9], b[9], i0, lin_w, y9, x0, N0);
}

// Round 7
// 658.785 us; speedup vs baseline: 1.1490x; 1.0793x over previous
//
#include <hip/hip_runtime.h>

#define EPSV 1e-5f

typedef __attribute__((ext_vector_type(8))) short short8;
typedef __attribute__((ext_vector_type(4))) float float4v;

static inline int cdiv(int a, int b) { return (a + b - 1) / b; }

__device__ inline unsigned short f2bf(float x) {
  unsigned u = __float_as_uint(x);
  return (unsigned short)((u + 0x7FFFu + ((u >> 16) & 1u)) >> 16);
}
__device__ inline float bf2f(unsigned short u) {
  return __uint_as_float(((unsigned)u) << 16);
}

struct PrepArgs {
  const float* w[10];
  unsigned short* wt[10];
  int ci[10];
  int co[10];
  int wcum[11];
  const float* feats;
  unsigned short* featsb;
  int nfeat4;
  float* stats;
};

// zero stats + feats fp32->bf16 + all 10 weights fp32->bf16 transposed [27][CO][CI]
__global__ __launch_bounds__(256) void prep_kernel(PrepArgs p) {
  long tid = (long)blockIdx.x * 256 + threadIdx.x;
  if (tid < 320) {
    ((float4*)p.stats)[tid] = make_float4(0.f, 0.f, 0.f, 0.f);
    return;
  }
  tid -= 320;
  if (tid < p.nfeat4) {
    float4 v = ((const float4*)p.feats)[tid];
    ushort4 r;
    r.x = f2bf(v.x); r.y = f2bf(v.y); r.z = f2bf(v.z); r.w = f2bf(v.w);
    ((ushort4*)p.featsb)[tid] = r;
    return;
  }
  tid -= p.nfeat4;
  if (tid >= p.wcum[10]) return;
  int i = 0;
  while (tid >= p.wcum[i + 1]) ++i;
  int e = (int)(tid - p.wcum[i]);
  int ci = p.ci[i], co = p.co[i];
  int k = e / (ci * co);
  int r = e - k * (ci * co);
  int o = r / ci;
  int c = r - o * ci;
  p.wt[i][((long)k * co + o) * ci + c] = f2bf(p.w[i][((long)k * ci + c) * co + o]);
}

// ================= MFMA gather-GEMM conv =================
// Wave = 16 output rows x (TILES*16) couts. A-frag gathered 16B/lane from bf16
// features; B-frag 16B/lane from transposed bf16 weights (L1-hot). Invalid
// neighbors -> zero fragment. Writes fp32 y + BN sum/sumsq stats.
template<int CI, int CO, int TILES>
__global__ __launch_bounds__(256) void conv_mfma(
    const unsigned short* __restrict__ f, const int* __restrict__ nbr,
    const unsigned short* __restrict__ wt, float* __restrict__ y,
    float* __restrict__ stats, int nout) {
  constexpr int TPC = (CI <= 32) ? (32 / CI) : 1;          // taps per K=32 chunk
  constexpr int NCHUNK = (CI <= 32) ? ((27 + TPC - 1) / TPC) : 54;
  constexpr int NTC = TILES * 16;
  __shared__ float s_red[2 * NTC];

  const int lane = threadIdx.x & 63;
  const int wid = threadIdx.x >> 6;
  const int m = lane & 15;
  const int quad = lane >> 4;
  const int rowbase = (blockIdx.x * 4 + wid) * 16;
  const int row = rowbase + m;
  const bool rok = row < nout;
  const int cbase = blockIdx.y * NTC;

  for (int i = threadIdx.x; i < 2 * NTC; i += 256) s_red[i] = 0.f;
  __syncthreads();

  float4v acc[TILES];
#pragma unroll
  for (int t = 0; t < TILES; ++t)
#pragma unroll
    for (int r = 0; r < 4; ++r) acc[t][r] = 0.f;

  auto tapof = [&](int c) -> int {
    if constexpr (CI == 64) return c >> 1;
    else return c * TPC + (quad * 8) / CI;
  };
  auto cioof = [&](int c) -> int {
    if constexpr (CI == 64) return ((c & 1) << 5) + quad * 8;
    else return (quad * 8) % CI;
  };
  auto loadA = [&](int c) -> short8 {
    short8 a;
#pragma unroll
    for (int j = 0; j < 8; ++j) a[j] = 0;
    int tap = tapof(c);
    if (rok && tap < 27) {
      int idx = nbr[(long)row * 27 + tap];
      if (idx >= 0) a = *(const short8*)(f + (long)idx * CI + cioof(c));
    }
    return a;
  };
  auto loadB = [&](int c, int t) -> short8 {
    short8 bq;
#pragma unroll
    for (int j = 0; j < 8; ++j) bq[j] = 0;
    int tap = tapof(c);
    int co = cbase + t * 16 + m;
    if (tap < 27 && co < CO)
      bq = *(const short8*)(wt + ((long)tap * CO + co) * CI + cioof(c));
    return bq;
  };

  short8 aN = loadA(0);
  short8 bN[TILES];
#pragma unroll
  for (int t = 0; t < TILES; ++t) bN[t] = loadB(0, t);

#pragma unroll 2
  for (int c = 0; c < NCHUNK; ++c) {
    short8 aC = aN;
    short8 bC[TILES];
#pragma unroll
    for (int t = 0; t < TILES; ++t) bC[t] = bN[t];
    if (c + 1 < NCHUNK) {
      aN = loadA(c + 1);
#pragma unroll
      for (int t = 0; t < TILES; ++t) bN[t] = loadB(c + 1, t);
    }
#pragma unroll
    for (int t = 0; t < TILES; ++t)
      acc[t] = __builtin_amdgcn_mfma_f32_16x16x32_bf16(aC, bC[t], acc[t], 0, 0, 0);
  }

  // D layout: col = lane&15 (cout), row = quad*4 + r
#pragma unroll
  for (int t = 0; t < TILES; ++t) {
    int co = cbase + t * 16 + m;
    float sum = 0.f, sq = 0.f;
#pragma unroll
    for (int r = 0; r < 4; ++r) {
      float v = acc[t][r];
      int orow = rowbase + quad * 4 + r;
      if (co < CO && orow < nout) y[(long)orow * CO + co] = v;
      sum += v;
      sq = fmaf(v, v, sq);
    }
    sum += __shfl_xor(sum, 16); sq += __shfl_xor(sq, 16);
    sum += __shfl_xor(sum, 32); sq += __shfl_xor(sq, 32);
    if (quad == 0) {
      atomicAdd(&s_red[t * 16 + m], sum);
      atomicAdd(&s_red[NTC + t * 16 + m], sq);
    }
  }
  __syncthreads();
  if ((int)threadIdx.x < NTC) {
    int co = cbase + threadIdx.x;
    if (co < CO) {
      atomicAdd(&stats[co], s_red[threadIdx.x]);
      atomicAdd(&stats[64 + co], s_red[NTC + threadIdx.x]);
    }
  }
}

// ---- BN+ReLU (+bf16 skip), fp32 y -> bf16 feature map ----
template<int CO>
__global__ __launch_bounds__(256) void bn_relu_bf16(
    const float* __restrict__ y, const float* __restrict__ stats,
    const float* __restrict__ g, const float* __restrict__ b,
    const unsigned short* __restrict__ skip, unsigned short* __restrict__ out,
    int nout, float inv_n) {
  long i4 = (long)blockIdx.x * 256 + threadIdx.x;
  long total4 = (long)nout * CO / 4;
  if (i4 >= total4) return;
  int o = (int)((i4 * 4) % CO);
  float4 v = ((const float4*)y)[i4];
  float vv[4] = {v.x, v.y, v.z, v.w};
  unsigned short rr[4];
#pragma unroll
  for (int j = 0; j < 4; ++j) {
    float mu = stats[o + j] * inv_n;
    float var = stats[64 + o + j] * inv_n - mu * mu;
    float a = g[o + j] * rsqrtf(var + EPSV);
    float cc = fmaf(-mu, a, b[o + j]);
    float x = fmaxf(fmaf(vv[j], a, cc), 0.f);
    if (skip) x += bf2f(skip[i4 * 4 + j]);
    rr[j] = f2bf(x);
  }
  ushort4 r;
  r.x = rr[0]; r.y = rr[1]; r.z = rr[2]; r.w = rr[3];
  ((ushort4*)out)[i4] = r;
}

// ---- fused tail: x0 = c0f + relu(bn(y9)); out0 = x0 @ lin_w.T (in place over y9) ----
__global__ __launch_bounds__(256) void tail_kernel(
    const unsigned short* __restrict__ c0f, const float* __restrict__ st9,
    const float* __restrict__ g9, const float* __restrict__ b9, float inv_n,
    const float* __restrict__ lin_w, float* y9out, float* __restrict__ x0, int n0) {
  __shared__ float swl[64];
  __shared__ float sbn[16];
  if (threadIdx.x < 64) swl[threadIdx.x] = lin_w[threadIdx.x];
  if (threadIdx.x < 8) {
    int o = threadIdx.x;
    float mu = st9[o] * inv_n;
    float var = st9[64 + o] * inv_n - mu * mu;
    float a = g9[o] * rsqrtf(var + EPSV);
    sbn[o] = a;
    sbn[8 + o] = fmaf(-mu, a, b9[o]);
  }
  __syncthreads();
  int n = blockIdx.x * 256 + threadIdx.x;
  if (n >= n0) return;
  const float4* pr = (const float4*)(y9out + (long)n * 8);
  float4 r0 = pr[0], r1 = pr[1];
  float rr[8] = {r0.x, r0.y, r0.z, r0.w, r1.x, r1.y, r1.z, r1.w};
  const ushort4* pc = (const ushort4*)(c0f + (long)n * 8);
  ushort4 c0 = pc[0], c1 = pc[1];
  unsigned short cs[8] = {c0.x, c0.y, c0.z, c0.w, c1.x, c1.y, c1.z, c1.w};
  float xv[8];
#pragma unroll
  for (int c = 0; c < 8; ++c)
    xv[c] = bf2f(cs[c]) + fmaxf(fmaf(rr[c], sbn[c], sbn[8 + c]), 0.f);
  *(float4*)(x0 + (long)n * 8) = make_float4(xv[0], xv[1], xv[2], xv[3]);
  *(float4*)(x0 + (long)n * 8 + 4) = make_float4(xv[4], xv[5], xv[6], xv[7]);
  float ov[8];
#pragma unroll
  for (int j = 0; j < 8; ++j) {
    float s = 0.f;
#pragma unroll
    for (int c = 0; c < 8; ++c) s = fmaf(xv[c], swl[j * 8 + c], s);
    ov[j] = s;
  }
  *(float4*)(y9out + (long)n * 8) = make_float4(ov[0], ov[1], ov[2], ov[3]);
  *(float4*)(y9out + (long)n * 8 + 4) = make_float4(ov[4], ov[5], ov[6], ov[7]);
}

extern "C" void kernel_launch(void* const* d_in, const int* in_sizes, int n_in,
                              void* d_out, int out_size, void* d_ws, size_t ws_size,
                              hipStream_t stream) {
  const float* feats   = (const float*)d_in[0];
  const int* nbr0      = (const int*)d_in[1];
  const int* nbr_d01   = (const int*)d_in[2];
  const int* nbr1      = (const int*)d_in[3];
  const int* nbr_d12   = (const int*)d_in[4];
  const int* nbr2      = (const int*)d_in[5];
  const int* nbr_d23   = (const int*)d_in[6];
  const int* nbr3      = (const int*)d_in[7];
  const int* nbr_u32   = (const int*)d_in[8];
  const int* nbr_u21   = (const int*)d_in[9];
  const int* nbr_u10   = (const int*)d_in[10];
  const float* w[10];
  const float* g[10];
  const float* b[10];
  for (int i = 0; i < 10; ++i) {
    w[i] = (const float*)d_in[11 + 3 * i];
    g[i] = (const float*)d_in[12 + 3 * i];
    b[i] = (const float*)d_in[13 + 3 * i];
  }
  const float* lin_w = (const float*)d_in[41];

  const int N0 = in_sizes[0] / 16;
  const int N1 = in_sizes[2] / 27;
  const int N2 = in_sizes[4] / 27;
  const int N3 = in_sizes[6] / 27;
  const float i0 = 1.f / N0, i1 = 1.f / N1, i2 = 1.f / N2, i3 = 1.f / N3;

  static const int CIv[10] = {16, 8, 16, 16, 32, 32, 64, 64, 32, 16};
  static const int COv[10] = {8, 16, 16, 32, 32, 64, 64, 32, 16, 8};

  // ---- workspace: fp32 region first, then bf16 (ushort) region ----
  float* stats = (float*)d_ws;                       // 1280 floats
  float* yraw  = stats + 1280;                       // max(N0*8, N1*16) = N1*16
  unsigned short* u = (unsigned short*)(yraw + (size_t)N1 * 16);

  unsigned short* wt[10];
  int wcum[11];
  wcum[0] = 0;
  for (int i = 0; i < 10; ++i) {
    wt[i] = u;
    int sz = 27 * CIv[i] * COv[i];
    u += sz;
    wcum[i + 1] = wcum[i] + sz;
  }
  unsigned short* featsb = u; u += (size_t)N0 * 16;
  unsigned short* c0f = u;    u += (size_t)N0 * 8;
  unsigned short* t1  = u;    u += (size_t)N1 * 16;
  unsigned short* c2f = u;    u += (size_t)N1 * 16;
  unsigned short* t2  = u;    u += (size_t)N2 * 32;
  unsigned short* c4f = u;    u += (size_t)N2 * 32;
  unsigned short* t3  = u;    u += (size_t)N3 * 64;
  unsigned short* t4  = u;    u += (size_t)N3 * 64;
  unsigned short* t5  = t2;   // reuse
  unsigned short* t6  = t1;   // reuse
  float* y9 = (float*)d_out;                         // conv9 raw staged in out region
  float* x0 = (float*)d_out + (size_t)N0 * 8;

  float* s[10];
  for (int i = 0; i < 10; ++i) s[i] = stats + i * 128;

  // ---- prep: zero stats, feats->bf16, weights->bf16 transposed ----
  PrepArgs pa;
  for (int i = 0; i < 10; ++i) {
    pa.w[i] = w[i]; pa.wt[i] = wt[i];
    pa.ci[i] = CIv[i]; pa.co[i] = COv[i];
    pa.wcum[i] = wcum[i];
  }
  pa.wcum[10] = wcum[10];
  pa.feats = feats; pa.featsb = featsb;
  pa.nfeat4 = N0 * 16 / 4;
  pa.stats = stats;
  long prep_total = 320L + pa.nfeat4 + wcum[10];
  prep_kernel<<<(int)((prep_total + 255) / 256), 256, 0, stream>>>(pa);

  auto bgrid = [](long nout, int co) { return (int)((nout * co / 4 + 255) / 256); };

  // conv0: 16->8 @ N0
  conv_mfma<16, 8, 1><<<dim3(cdiv(N0, 64), 1), 256, 0, stream>>>(featsb, nbr0, wt[0], yraw, s[0], N0);
  bn_relu_bf16<8><<<bgrid(N0, 8), 256, 0, stream>>>(yraw, s[0], g[0], b[0], nullptr, c0f, N0, i0);

  // conv1: 8->16 down to N1
  conv_mfma<8, 16, 1><<<dim3(cdiv(N1, 64), 1), 256, 0, stream>>>(c0f, nbr_d01, wt[1], yraw, s[1], N1);
  bn_relu_bf16<16><<<bgrid(N1, 16), 256, 0, stream>>>(yraw, s[1], g[1], b[1], nullptr, t1, N1, i1);

  // conv2: 16->16 @ N1
  conv_mfma<16, 16, 1><<<dim3(cdiv(N1, 64), 1), 256, 0, stream>>>(t1, nbr1, wt[2], yraw, s[2], N1);
  bn_relu_bf16<16><<<bgrid(N1, 16), 256, 0, stream>>>(yraw, s[2], g[2], b[2], nullptr, c2f, N1, i1);

  // conv3: 16->32 down to N2
  conv_mfma<16, 32, 2><<<dim3(cdiv(N2, 64), 1), 256, 0, stream>>>(c2f, nbr_d12, wt[3], yraw, s[3], N2);
  bn_relu_bf16<32><<<bgrid(N2, 32), 256, 0, stream>>>(yraw, s[3], g[3], b[3], nullptr, t2, N2, i2);

  // conv4: 32->32 @ N2
  conv_mfma<32, 32, 2><<<dim3(cdiv(N2, 64), 1), 256, 0, stream>>>(t2, nbr2, wt[4], yraw, s[4], N2);
  bn_relu_bf16<32><<<bgrid(N2, 32), 256, 0, stream>>>(yraw, s[4], g[4], b[4], nullptr, c4f, N2, i2);

  // conv5: 32->64 down to N3 (cout split over gridDim.y for parallelism)
  conv_mfma<32, 64, 1><<<dim3(cdiv(N3, 64), 4), 256, 0, stream>>>(c4f, nbr_d23, wt[5], yraw, s[5], N3);
  bn_relu_bf16<64><<<bgrid(N3, 64), 256, 0, stream>>>(yraw, s[5], g[5], b[5], nullptr, t3, N3, i3);

  // conv6: 64->64 @ N3
  conv_mfma<64, 64, 1><<<dim3(cdiv(N3, 64), 4), 256, 0, stream>>>(t3, nbr3, wt[6], yraw, s[6], N3);
  bn_relu_bf16<64><<<bgrid(N3, 64), 256, 0, stream>>>(yraw, s[6], g[6], b[6], nullptr, t4, N3, i3);

  // conv7: 64->32 up to N2; x2 = c4f + relu(bn(y7))
  conv_mfma<64, 32, 2><<<dim3(cdiv(N2, 64), 1), 256, 0, stream>>>(t4, nbr_u32, wt[7], yraw, s[7], N2);
  bn_relu_bf16<32><<<bgrid(N2, 32), 256, 0, stream>>>(yraw, s[7], g[7], b[7], c4f, t5, N2, i2);

  // conv8: 32->16 up to N1; x1 = c2f + relu(bn(y8))
  conv_mfma<32, 16, 1><<<dim3(cdiv(N1, 64), 1), 256, 0, stream>>>(t5, nbr_u21, wt[8], yraw, s[8], N1);
  bn_relu_bf16<16><<<bgrid(N1, 16), 256, 0, stream>>>(yraw, s[8], g[8], b[8], c2f, t6, N1, i1);

  // conv9: 16->8 up to N0; raw y9 staged in out region
  conv_mfma<16, 8, 1><<<dim3(cdiv(N0, 64), 1), 256, 0, stream>>>(t6, nbr_u10, wt[9], y9, s[9], N0);

  // tail: x0 = c0f + relu(bn(y9)); out0 = x0 @ lin_w.T
  tail_kernel<<<cdiv(N0, 256), 256, 0, stream>>>(c0f, s[9], g[9], b[9], i0, lin_w, y9, x0, N0);
}

// Round 8
// 620.480 us; speedup vs baseline: 1.2200x; 1.0617x over previous
//
#include <hip/hip_runtime.h>

#define EPSV 1e-5f

typedef __attribute__((ext_vector_type(8))) short short8;
typedef __attribute__((ext_vector_type(4))) float float4v;

static inline int cdiv(int a, int b) { return (a + b - 1) / b; }

__device__ inline unsigned short f2bf(float x) {
  unsigned u = __float_as_uint(x);
  return (unsigned short)((u + 0x7FFFu + ((u >> 16) & 1u)) >> 16);
}
__device__ inline float bf2f(unsigned short u) {
  return __uint_as_float(((unsigned)u) << 16);
}

struct PrepArgs {
  const float* w[10];
  unsigned short* wt[10];
  int ci[10];
  int co[10];
  int wcum[11];
  const float* feats;
  unsigned short* featsb;
  int nfeat4;
  float* stats;
};

// zero stats + feats fp32->bf16 + all 10 weights fp32->bf16 transposed [27][CO][CI]
__global__ __launch_bounds__(256) void prep_kernel(PrepArgs p) {
  long tid = (long)blockIdx.x * 256 + threadIdx.x;
  if (tid < 320) {
    ((float4*)p.stats)[tid] = make_float4(0.f, 0.f, 0.f, 0.f);
    return;
  }
  tid -= 320;
  if (tid < p.nfeat4) {
    float4 v = ((const float4*)p.feats)[tid];
    ushort4 r;
    r.x = f2bf(v.x); r.y = f2bf(v.y); r.z = f2bf(v.z); r.w = f2bf(v.w);
    ((ushort4*)p.featsb)[tid] = r;
    return;
  }
  tid -= p.nfeat4;
  if (tid >= p.wcum[10]) return;
  int i = 0;
  while (tid >= p.wcum[i + 1]) ++i;
  int e = (int)(tid - p.wcum[i]);
  int ci = p.ci[i], co = p.co[i];
  int k = e / (ci * co);
  int r = e - k * (ci * co);
  int o = r / ci;
  int c = r - o * ci;
  p.wt[i][((long)k * co + o) * ci + c] = f2bf(p.w[i][((long)k * ci + c) * co + o]);
}

// ================= MFMA gather-GEMM conv, deep-pipelined =================
// Block = 4 waves = 64 output rows, one 16-cout slice (blockIdx.y).
// nbr rows staged in LDS (kills dependent nbr->gather chain). Chunks processed
// in groups of G, double-buffered in registers: G A-gathers + G B-loads for
// group g+1 in flight while group g's MFMAs execute.
template<int CI, int CO>
__global__ __launch_bounds__(256) void conv_mfma(
    const unsigned short* __restrict__ f, const int* __restrict__ nbr,
    const unsigned short* __restrict__ wt, float* __restrict__ y,
    float* __restrict__ stats, int nout) {
  constexpr int NCHUNK = (CI == 8) ? 7 : (CI == 16) ? 14 : (CI == 32) ? 27 : 54;
  constexpr int G = (CI <= 16) ? 7 : 9;   // exact divisor of NCHUNK (w/ tap<27 pad)
  constexpr int NG = (NCHUNK + G - 1) / G;
  __shared__ int sNbr[64 * 27];
  __shared__ float s_red[32];

  const int tid = threadIdx.x;
  const int lane = tid & 63;
  const int wid = tid >> 6;
  const int m = lane & 15;
  const int quad = lane >> 4;
  const int blockrow = blockIdx.x * 64;
  const int mloc = wid * 16 + m;
  const int cbase = blockIdx.y * 16;
  const int co = cbase + m;
  const bool cok = co < CO;

  for (int i = tid; i < 64 * 27; i += 256) {
    int r = blockrow + i / 27;
    sNbr[i] = (r < nout) ? nbr[(long)r * 27 + (i % 27)] : -1;
  }
  if (tid < 32) s_red[tid] = 0.f;
  __syncthreads();

  auto tapof = [&](int c) -> int {
    if constexpr (CI == 8) return c * 4 + quad;
    else if constexpr (CI == 16) return c * 2 + (quad >> 1);
    else if constexpr (CI == 32) return c;
    else return c >> 1;
  };
  auto cioof = [&](int c) -> int {
    if constexpr (CI == 8) return 0;
    else if constexpr (CI == 16) return (quad & 1) * 8;
    else if constexpr (CI == 32) return quad * 8;
    else return ((c & 1) << 5) + quad * 8;
  };

  short8 A[2][G], B[2][G];
  auto load_group = [&](int g, int bufi) {
#pragma unroll
    for (int j = 0; j < G; ++j) {
      const int c = g * G + j;
      const int tap = tapof(c);
      short8 a, bq;
#pragma unroll
      for (int q = 0; q < 8; ++q) { a[q] = 0; bq[q] = 0; }
      if (tap < 27) {
        int idx = sNbr[mloc * 27 + tap];
        if (idx >= 0) a = *(const short8*)(f + (long)idx * CI + cioof(c));
        if (cok) bq = *(const short8*)(wt + ((long)tap * CO + co) * CI + cioof(c));
      }
      A[bufi][j] = a;
      B[bufi][j] = bq;
    }
  };

  float4v acc = {0.f, 0.f, 0.f, 0.f};
  load_group(0, 0);
#pragma unroll
  for (int g = 0; g < NG; ++g) {
    const int cur = g & 1;
    if (g + 1 < NG) load_group(g + 1, cur ^ 1);
#pragma unroll
    for (int j = 0; j < G; ++j)
      acc = __builtin_amdgcn_mfma_f32_16x16x32_bf16(A[cur][j], B[cur][j], acc, 0, 0, 0);
  }

  // D layout: col = lane&15 (cout), row = quad*4 + r
  float sum = 0.f, sq = 0.f;
#pragma unroll
  for (int r = 0; r < 4; ++r) {
    float v = acc[r];
    int orow = blockrow + wid * 16 + quad * 4 + r;
    if (cok && orow < nout) y[(long)orow * CO + co] = v;
    sum += v;
    sq = fmaf(v, v, sq);
  }
  sum += __shfl_xor(sum, 16); sq += __shfl_xor(sq, 16);
  sum += __shfl_xor(sum, 32); sq += __shfl_xor(sq, 32);
  if (quad == 0 && cok) {
    atomicAdd(&s_red[m], sum);
    atomicAdd(&s_red[16 + m], sq);
  }
  __syncthreads();
  if (tid < 16 && cbase + tid < CO) {
    atomicAdd(&stats[cbase + tid], s_red[tid]);
    atomicAdd(&stats[64 + cbase + tid], s_red[16 + tid]);
  }
}

// ---- BN+ReLU (+bf16 skip), fp32 y -> bf16 feature map ----
template<int CO>
__global__ __launch_bounds__(256) void bn_relu_bf16(
    const float* __restrict__ y, const float* __restrict__ stats,
    const float* __restrict__ g, const float* __restrict__ b,
    const unsigned short* __restrict__ skip, unsigned short* __restrict__ out,
    int nout, float inv_n) {
  long i4 = (long)blockIdx.x * 256 + threadIdx.x;
  long total4 = (long)nout * CO / 4;
  if (i4 >= total4) return;
  int o = (int)((i4 * 4) % CO);
  float4 v = ((const float4*)y)[i4];
  float vv[4] = {v.x, v.y, v.z, v.w};
  unsigned short rr[4];
#pragma unroll
  for (int j = 0; j < 4; ++j) {
    float mu = stats[o + j] * inv_n;
    float var = stats[64 + o + j] * inv_n - mu * mu;
    float a = g[o + j] * rsqrtf(var + EPSV);
    float cc = fmaf(-mu, a, b[o + j]);
    float x = fmaxf(fmaf(vv[j], a, cc), 0.f);
    if (skip) x += bf2f(skip[i4 * 4 + j]);
    rr[j] = f2bf(x);
  }
  ushort4 r;
  r.x = rr[0]; r.y = rr[1]; r.z = rr[2]; r.w = rr[3];
  ((ushort4*)out)[i4] = r;
}

// ---- fused tail: x0 = c0f + relu(bn(y9)); out0 = x0 @ lin_w.T (in place over y9) ----
__global__ __launch_bounds__(256) void tail_kernel(
    const unsigned short* __restrict__ c0f, const float* __restrict__ st9,
    const float* __restrict__ g9, const float* __restrict__ b9, float inv_n,
    const float* __restrict__ lin_w, float* y9out, float* __restrict__ x0, int n0) {
  __shared__ float swl[64];
  __shared__ float sbn[16];
  if (threadIdx.x < 64) swl[threadIdx.x] = lin_w[threadIdx.x];
  if (threadIdx.x < 8) {
    int o = threadIdx.x;
    float mu = st9[o] * inv_n;
    float var = st9[64 + o] * inv_n - mu * mu;
    float a = g9[o] * rsqrtf(var + EPSV);
    sbn[o] = a;
    sbn[8 + o] = fmaf(-mu, a, b9[o]);
  }
  __syncthreads();
  int n = blockIdx.x * 256 + threadIdx.x;
  if (n >= n0) return;
  const float4* pr = (const float4*)(y9out + (long)n * 8);
  float4 r0 = pr[0], r1 = pr[1];
  float rr[8] = {r0.x, r0.y, r0.z, r0.w, r1.x, r1.y, r1.z, r1.w};
  const ushort4* pc = (const ushort4*)(c0f + (long)n * 8);
  ushort4 c0 = pc[0], c1 = pc[1];
  unsigned short cs[8] = {c0.x, c0.y, c0.z, c0.w, c1.x, c1.y, c1.z, c1.w};
  float xv[8];
#pragma unroll
  for (int c = 0; c < 8; ++c)
    xv[c] = bf2f(cs[c]) + fmaxf(fmaf(rr[c], sbn[c], sbn[8 + c]), 0.f);
  *(float4*)(x0 + (long)n * 8) = make_float4(xv[0], xv[1], xv[2], xv[3]);
  *(float4*)(x0 + (long)n * 8 + 4) = make_float4(xv[4], xv[5], xv[6], xv[7]);
  float ov[8];
#pragma unroll
  for (int j = 0; j < 8; ++j) {
    float s = 0.f;
#pragma unroll
    for (int c = 0; c < 8; ++c) s = fmaf(xv[c], swl[j * 8 + c], s);
    ov[j] = s;
  }
  *(float4*)(y9out + (long)n * 8) = make_float4(ov[0], ov[1], ov[2], ov[3]);
  *(float4*)(y9out + (long)n * 8 + 4) = make_float4(ov[4], ov[5], ov[6], ov[7]);
}

extern "C" void kernel_launch(void* const* d_in, const int* in_sizes, int n_in,
                              void* d_out, int out_size, void* d_ws, size_t ws_size,
                              hipStream_t stream) {
  const float* feats   = (const float*)d_in[0];
  const int* nbr0      = (const int*)d_in[1];
  const int* nbr_d01   = (const int*)d_in[2];
  const int* nbr1      = (const int*)d_in[3];
  const int* nbr_d12   = (const int*)d_in[4];
  const int* nbr2      = (const int*)d_in[5];
  const int* nbr_d23   = (const int*)d_in[6];
  const int* nbr3      = (const int*)d_in[7];
  const int* nbr_u32   = (const int*)d_in[8];
  const int* nbr_u21   = (const int*)d_in[9];
  const int* nbr_u10   = (const int*)d_in[10];
  const float* w[10];
  const float* g[10];
  const float* b[10];
  for (int i = 0; i < 10; ++i) {
    w[i] = (const float*)d_in[11 + 3 * i];
    g[i] = (const float*)d_in[12 + 3 * i];
    b[i] = (const float*)d_in[13 + 3 * i];
  }
  const float* lin_w = (const float*)d_in[41];

  const int N0 = in_sizes[0] / 16;
  const int N1 = in_sizes[2] / 27;
  const int N2 = in_sizes[4] / 27;
  const int N3 = in_sizes[6] / 27;
  const float i0 = 1.f / N0, i1 = 1.f / N1, i2 = 1.f / N2, i3 = 1.f / N3;

  static const int CIv[10] = {16, 8, 16, 16, 32, 32, 64, 64, 32, 16};
  static const int COv[10] = {8, 16, 16, 32, 32, 64, 64, 32, 16, 8};

  // ---- workspace: fp32 region first, then bf16 (ushort) region ----
  float* stats = (float*)d_ws;                       // 1280 floats
  float* yraw  = stats + 1280;                       // max raw y = N1*16
  unsigned short* u = (unsigned short*)(yraw + (size_t)N1 * 16);

  unsigned short* wt[10];
  int wcum[11];
  wcum[0] = 0;
  for (int i = 0; i < 10; ++i) {
    wt[i] = u;
    int sz = 27 * CIv[i] * COv[i];
    u += sz;
    wcum[i + 1] = wcum[i] + sz;
  }
  unsigned short* featsb = u; u += (size_t)N0 * 16;
  unsigned short* c0f = u;    u += (size_t)N0 * 8;
  unsigned short* t1  = u;    u += (size_t)N1 * 16;
  unsigned short* c2f = u;    u += (size_t)N1 * 16;
  unsigned short* t2  = u;    u += (size_t)N2 * 32;
  unsigned short* c4f = u;    u += (size_t)N2 * 32;
  unsigned short* t3  = u;    u += (size_t)N3 * 64;
  unsigned short* t4  = u;    u += (size_t)N3 * 64;
  unsigned short* t5  = t2;   // reuse
  unsigned short* t6  = t1;   // reuse
  float* y9 = (float*)d_out;                         // conv9 raw staged in out region
  float* x0 = (float*)d_out + (size_t)N0 * 8;

  float* s[10];
  for (int i = 0; i < 10; ++i) s[i] = stats + i * 128;

  // ---- prep: zero stats, feats->bf16, weights->bf16 transposed ----
  PrepArgs pa;
  for (int i = 0; i < 10; ++i) {
    pa.w[i] = w[i]; pa.wt[i] = wt[i];
    pa.ci[i] = CIv[i]; pa.co[i] = COv[i];
    pa.wcum[i] = wcum[i];
  }
  pa.wcum[10] = wcum[10];
  pa.feats = feats; pa.featsb = featsb;
  pa.nfeat4 = N0 * 16 / 4;
  pa.stats = stats;
  long prep_total = 320L + pa.nfeat4 + wcum[10];
  prep_kernel<<<(int)((prep_total + 255) / 256), 256, 0, stream>>>(pa);

  auto bgrid = [](long nout, int co) { return (int)((nout * co / 4 + 255) / 256); };

  // conv0: 16->8 @ N0
  conv_mfma<16, 8><<<dim3(cdiv(N0, 64), 1), 256, 0, stream>>>(featsb, nbr0, wt[0], yraw, s[0], N0);
  bn_relu_bf16<8><<<bgrid(N0, 8), 256, 0, stream>>>(yraw, s[0], g[0], b[0], nullptr, c0f, N0, i0);

  // conv1: 8->16 down to N1
  conv_mfma<8, 16><<<dim3(cdiv(N1, 64), 1), 256, 0, stream>>>(c0f, nbr_d01, wt[1], yraw, s[1], N1);
  bn_relu_bf16<16><<<bgrid(N1, 16), 256, 0, stream>>>(yraw, s[1], g[1], b[1], nullptr, t1, N1, i1);

  // conv2: 16->16 @ N1
  conv_mfma<16, 16><<<dim3(cdiv(N1, 64), 1), 256, 0, stream>>>(t1, nbr1, wt[2], yraw, s[2], N1);
  bn_relu_bf16<16><<<bgrid(N1, 16), 256, 0, stream>>>(yraw, s[2], g[2], b[2], nullptr, c2f, N1, i1);

  // conv3: 16->32 down to N2
  conv_mfma<16, 32><<<dim3(cdiv(N2, 64), 2), 256, 0, stream>>>(c2f, nbr_d12, wt[3], yraw, s[3], N2);
  bn_relu_bf16<32><<<bgrid(N2, 32), 256, 0, stream>>>(yraw, s[3], g[3], b[3], nullptr, t2, N2, i2);

  // conv4: 32->32 @ N2
  conv_mfma<32, 32><<<dim3(cdiv(N2, 64), 2), 256, 0, stream>>>(t2, nbr2, wt[4], yraw, s[4], N2);
  bn_relu_bf16<32><<<bgrid(N2, 32), 256, 0, stream>>>(yraw, s[4], g[4], b[4], nullptr, c4f, N2, i2);

  // conv5: 32->64 down to N3
  conv_mfma<32, 64><<<dim3(cdiv(N3, 64), 4), 256, 0, stream>>>(c4f, nbr_d23, wt[5], yraw, s[5], N3);
  bn_relu_bf16<64><<<bgrid(N3, 64), 256, 0, stream>>>(yraw, s[5], g[5], b[5], nullptr, t3, N3, i3);

  // conv6: 64->64 @ N3
  conv_mfma<64, 64><<<dim3(cdiv(N3, 64), 4), 256, 0, stream>>>(t3, nbr3, wt[6], yraw, s[6], N3);
  bn_relu_bf16<64><<<bgrid(N3, 64), 256, 0, stream>>>(yraw, s[6], g[6], b[6], nullptr, t4, N3, i3);

  // conv7: 64->32 up to N2; x2 = c4f + relu(bn(y7))
  conv_mfma<64, 32><<<dim3(cdiv(N2, 64), 2), 256, 0, stream>>>(t4, nbr_u32, wt[7], yraw, s[7], N2);
  bn_relu_bf16<32><<<bgrid(N2, 32), 256, 0, stream>>>(yraw, s[7], g[7], b[7], c4f, t5, N2, i2);

  // conv8: 32->16 up to N1; x1 = c2f + relu(bn(y8))
  conv_mfma<32, 16><<<dim3(cdiv(N1, 64), 1), 256, 0, stream>>>(t5, nbr_u21, wt[8], yraw, s[8], N1);
  bn_relu_bf16<16><<<bgrid(N1, 16), 256, 0, stream>>>(yraw, s[8], g[8], b[8], c2f, t6, N1, i1);

  // conv9: 16->8 up to N0; raw y9 staged in out region
  conv_mfma<16, 8><<<dim3(cdiv(N0, 64), 1), 256, 0, stream>>>(t6, nbr_u10, wt[9], y9, s[9], N0);

  // tail: x0 = c0f + relu(bn(y9)); out0 = x0 @ lin_w.T
  tail_kernel<<<cdiv(N0, 256), 256, 0, stream>>>(c0f, s[9], g[9], b[9], i0, lin_w, y9, x0, N0);
}

// Round 9
// 489.767 us; speedup vs baseline: 1.5456x; 1.2669x over previous
//
#include <hip/hip_runtime.h>

#define EPSV 1e-5f

typedef __attribute__((ext_vector_type(8))) short short8;
typedef __attribute__((ext_vector_type(4))) float float4v;

static inline int cdiv(int a, int b) { return (a + b - 1) / b; }

__device__ inline unsigned short f2bf(float x) {
  unsigned u = __float_as_uint(x);
  return (unsigned short)((u + 0x7FFFu + ((u >> 16) & 1u)) >> 16);
}
__device__ inline float bf2f(unsigned short u) {
  return __uint_as_float(((unsigned)u) << 16);
}

#define NBUCKET 16

struct PrepArgs {
  const float* w[10];
  unsigned short* wt[10];
  int ci[10];
  int co[10];
  int wcum[11];
  const float* feats;
  unsigned short* featsb;
  int nfeat4;
  float* stats;
};

// zero stats + feats fp32->bf16 + all 10 weights fp32->bf16 transposed [27][CO][CI]
__global__ __launch_bounds__(256) void prep_kernel(PrepArgs p) {
  long tid = (long)blockIdx.x * 256 + threadIdx.x;
  const int nstat4 = 10 * NBUCKET * 128 / 4;
  if (tid < nstat4) {
    ((float4*)p.stats)[tid] = make_float4(0.f, 0.f, 0.f, 0.f);
    return;
  }
  tid -= nstat4;
  if (tid < p.nfeat4) {
    float4 v = ((const float4*)p.feats)[tid];
    ushort4 r;
    r.x = f2bf(v.x); r.y = f2bf(v.y); r.z = f2bf(v.z); r.w = f2bf(v.w);
    ((ushort4*)p.featsb)[tid] = r;
    return;
  }
  tid -= p.nfeat4;
  if (tid >= p.wcum[10]) return;
  int i = 0;
  while (tid >= p.wcum[i + 1]) ++i;
  int e = (int)(tid - p.wcum[i]);
  int ci = p.ci[i], co = p.co[i];
  int k = e / (ci * co);
  int r = e - k * (ci * co);
  int o = r / ci;
  int c = r - o * ci;
  p.wt[i][((long)k * co + o) * ci + c] = f2bf(p.w[i][((long)k * ci + c) * co + o]);
}

// ================= MFMA gather-GEMM conv, register-resident pipeline =================
// Block = 4 waves = 64 output rows x one 16-cout slice (blockIdx.y). No LDS, no
// barriers in the main path: per-lane direct nbr loads (L1-dedup across quads),
// then A/B gathers held in registers for max memory-level parallelism.
template<int CI, int CO>
__global__ __launch_bounds__(256) void conv_mfma(
    const unsigned short* __restrict__ f, const int* __restrict__ nbr,
    const unsigned short* __restrict__ wt, float* __restrict__ y,
    float* __restrict__ stats, int nout, int nxb) {
  constexpr int NCHUNK = (CI == 8) ? 7 : (CI == 16) ? 14 : (CI == 32) ? 27 : 54;

  // XCD-contiguous swizzle: block bx -> xb so each XCD works a contiguous slice
  int bx = blockIdx.x, xb;
  {
    int S8 = nxb >> 3;
    if (bx < (S8 << 3)) xb = (bx & 7) * S8 + (bx >> 3);
    else xb = bx;
  }

  const int tid = threadIdx.x;
  const int lane = tid & 63;
  const int wid = tid >> 6;
  const int m = lane & 15;
  const int quad = lane >> 4;
  const int blockrow = xb * 64;
  const int row = blockrow + wid * 16 + m;
  const bool rok = row < nout;
  const int cbase = blockIdx.y * 16;
  const int co = cbase + m;
  const bool cok = co < CO;

  auto tapof = [&](int c) -> int {
    if constexpr (CI == 8) return c * 4 + quad;
    else if constexpr (CI == 16) return c * 2 + (quad >> 1);
    else if constexpr (CI == 32) return c;
    else return c >> 1;
  };
  auto cioof = [&](int c) -> int {
    if constexpr (CI == 8) return 0;
    else if constexpr (CI == 16) return (quad & 1) * 8;
    else if constexpr (CI == 32) return quad * 8;
    else return ((c & 1) << 5) + quad * 8;
  };

  float4v acc = {0.f, 0.f, 0.f, 0.f};

  if constexpr (CI <= 16) {
    // ---- flat: all idx + A + B register-resident ----
    int idxs[NCHUNK];
#pragma unroll
    for (int c = 0; c < NCHUNK; ++c) {
      int tap = tapof(c);
      idxs[c] = (rok && tap < 27) ? nbr[(long)row * 27 + tap] : -1;
    }
    short8 A[NCHUNK], B[NCHUNK];
#pragma unroll
    for (int c = 0; c < NCHUNK; ++c) {
      int tap = tapof(c);
      short8 a, bq;
#pragma unroll
      for (int q = 0; q < 8; ++q) { a[q] = 0; bq[q] = 0; }
      if (idxs[c] >= 0) a = *(const short8*)(f + (long)idxs[c] * CI + cioof(c));
      if (cok && tap < 27) bq = *(const short8*)(wt + ((long)tap * CO + co) * CI + cioof(c));
      A[c] = a; B[c] = bq;
    }
#pragma unroll
    for (int c = 0; c < NCHUNK; ++c)
      acc = __builtin_amdgcn_mfma_f32_16x16x32_bf16(A[c], B[c], acc, 0, 0, 0);
  } else {
    // ---- grouped: prefetch all 27 idx, double-buffer A/B groups of 9 ----
    constexpr int G = 9;
    constexpr int NG = NCHUNK / G;
    int idxs[27];
#pragma unroll
    for (int t = 0; t < 27; ++t)
      idxs[t] = rok ? nbr[(long)row * 27 + t] : -1;

    short8 A[2][G], B[2][G];
    auto load_group = [&](int g, int bi) {
#pragma unroll
      for (int j = 0; j < G; ++j) {
        const int c = g * G + j;
        const int tap = tapof(c);
        short8 a, bq;
#pragma unroll
        for (int q = 0; q < 8; ++q) { a[q] = 0; bq[q] = 0; }
        int idx = idxs[tap];
        if (idx >= 0) a = *(const short8*)(f + (long)idx * CI + cioof(c));
        if (cok) bq = *(const short8*)(wt + ((long)tap * CO + co) * CI + cioof(c));
        A[bi][j] = a; B[bi][j] = bq;
      }
    };
    load_group(0, 0);
#pragma unroll
    for (int g = 0; g < NG; ++g) {
      const int cur = g & 1;
      if (g + 1 < NG) load_group(g + 1, cur ^ 1);
#pragma unroll
      for (int j = 0; j < G; ++j)
        acc = __builtin_amdgcn_mfma_f32_16x16x32_bf16(A[cur][j], B[cur][j], acc, 0, 0, 0);
    }
  }

  // D layout: col = lane&15 (cout), row = quad*4 + r
  float sum = 0.f, sq = 0.f;
#pragma unroll
  for (int r = 0; r < 4; ++r) {
    float v = acc[r];
    int orow = blockrow + wid * 16 + quad * 4 + r;
    if (cok && orow < nout) y[(long)orow * CO + co] = v;
    sum += v;
    sq = fmaf(v, v, sq);
  }
  sum += __shfl_xor(sum, 16); sq += __shfl_xor(sq, 16);
  sum += __shfl_xor(sum, 32); sq += __shfl_xor(sq, 32);
  if (quad == 0 && cok) {
    float* st = stats + (((unsigned)xb & (NBUCKET - 1)) << 7);
    atomicAdd(&st[co], sum);
    atomicAdd(&st[64 + co], sq);
  }
}

// ---- BN+ReLU (+bf16 skip), fp32 y -> bf16 feature map ----
template<int CO>
__global__ __launch_bounds__(256) void bn_relu_bf16(
    const float* __restrict__ y, const float* __restrict__ stats,
    const float* __restrict__ g, const float* __restrict__ b,
    const unsigned short* __restrict__ skip, unsigned short* __restrict__ out,
    int nout, float inv_n) {
  __shared__ float sA[CO], sC[CO];
  if ((int)threadIdx.x < CO) {
    int o = threadIdx.x;
    float su = 0.f, sq = 0.f;
#pragma unroll
    for (int bk = 0; bk < NBUCKET; ++bk) {
      su += stats[bk * 128 + o];
      sq += stats[bk * 128 + 64 + o];
    }
    float mu = su * inv_n;
    float var = sq * inv_n - mu * mu;
    float a = g[o] * rsqrtf(var + EPSV);
    sA[o] = a;
    sC[o] = fmaf(-mu, a, b[o]);
  }
  __syncthreads();
  long i4 = (long)blockIdx.x * 256 + threadIdx.x;
  long total4 = (long)nout * CO / 4;
  if (i4 >= total4) return;
  int o = (int)((i4 * 4) % CO);
  float4 v = ((const float4*)y)[i4];
  float vv[4] = {v.x, v.y, v.z, v.w};
  unsigned short rr[4];
#pragma unroll
  for (int j = 0; j < 4; ++j) {
    float x = fmaxf(fmaf(vv[j], sA[o + j], sC[o + j]), 0.f);
    if (skip) x += bf2f(skip[i4 * 4 + j]);
    rr[j] = f2bf(x);
  }
  ushort4 r;
  r.x = rr[0]; r.y = rr[1]; r.z = rr[2]; r.w = rr[3];
  ((ushort4*)out)[i4] = r;
}

// ---- fused tail: x0 = c0f + relu(bn(y9)); out0 = x0 @ lin_w.T (in place over y9) ----
__global__ __launch_bounds__(256) void tail_kernel(
    const unsigned short* __restrict__ c0f, const float* __restrict__ st9,
    const float* __restrict__ g9, const float* __restrict__ b9, float inv_n,
    const float* __restrict__ lin_w, float* y9out, float* __restrict__ x0, int n0) {
  __shared__ float swl[64];
  __shared__ float sbn[16];
  if (threadIdx.x < 64) swl[threadIdx.x] = lin_w[threadIdx.x];
  if (threadIdx.x < 8) {
    int o = threadIdx.x;
    float su = 0.f, sq = 0.f;
#pragma unroll
    for (int bk = 0; bk < NBUCKET; ++bk) {
      su += st9[bk * 128 + o];
      sq += st9[bk * 128 + 64 + o];
    }
    float mu = su * inv_n;
    float var = sq * inv_n - mu * mu;
    float a = g9[o] * rsqrtf(var + EPSV);
    sbn[o] = a;
    sbn[8 + o] = fmaf(-mu, a, b9[o]);
  }
  __syncthreads();
  int n = blockIdx.x * 256 + threadIdx.x;
  if (n >= n0) return;
  const float4* pr = (const float4*)(y9out + (long)n * 8);
  float4 r0 = pr[0], r1 = pr[1];
  float rr[8] = {r0.x, r0.y, r0.z, r0.w, r1.x, r1.y, r1.z, r1.w};
  const ushort4* pc = (const ushort4*)(c0f + (long)n * 8);
  ushort4 c0 = pc[0], c1 = pc[1];
  unsigned short cs[8] = {c0.x, c0.y, c0.z, c0.w, c1.x, c1.y, c1.z, c1.w};
  float xv[8];
#pragma unroll
  for (int c = 0; c < 8; ++c)
    xv[c] = bf2f(cs[c]) + fmaxf(fmaf(rr[c], sbn[c], sbn[8 + c]), 0.f);
  *(float4*)(x0 + (long)n * 8) = make_float4(xv[0], xv[1], xv[2], xv[3]);
  *(float4*)(x0 + (long)n * 8 + 4) = make_float4(xv[4], xv[5], xv[6], xv[7]);
  float ov[8];
#pragma unroll
  for (int j = 0; j < 8; ++j) {
    float s = 0.f;
#pragma unroll
    for (int c = 0; c < 8; ++c) s = fmaf(xv[c], swl[j * 8 + c], s);
    ov[j] = s;
  }
  *(float4*)(y9out + (long)n * 8) = make_float4(ov[0], ov[1], ov[2], ov[3]);
  *(float4*)(y9out + (long)n * 8 + 4) = make_float4(ov[4], ov[5], ov[6], ov[7]);
}

extern "C" void kernel_launch(void* const* d_in, const int* in_sizes, int n_in,
                              void* d_out, int out_size, void* d_ws, size_t ws_size,
                              hipStream_t stream) {
  const float* feats   = (const float*)d_in[0];
  const int* nbr0      = (const int*)d_in[1];
  const int* nbr_d01   = (const int*)d_in[2];
  const int* nbr1      = (const int*)d_in[3];
  const int* nbr_d12   = (const int*)d_in[4];
  const int* nbr2      = (const int*)d_in[5];
  const int* nbr_d23   = (const int*)d_in[6];
  const int* nbr3      = (const int*)d_in[7];
  const int* nbr_u32   = (const int*)d_in[8];
  const int* nbr_u21   = (const int*)d_in[9];
  const int* nbr_u10   = (const int*)d_in[10];
  const float* w[10];
  const float* g[10];
  const float* b[10];
  for (int i = 0; i < 10; ++i) {
    w[i] = (const float*)d_in[11 + 3 * i];
    g[i] = (const float*)d_in[12 + 3 * i];
    b[i] = (const float*)d_in[13 + 3 * i];
  }
  const float* lin_w = (const float*)d_in[41];

  const int N0 = in_sizes[0] / 16;
  const int N1 = in_sizes[2] / 27;
  const int N2 = in_sizes[4] / 27;
  const int N3 = in_sizes[6] / 27;
  const float i0 = 1.f / N0, i1 = 1.f / N1, i2 = 1.f / N2, i3 = 1.f / N3;

  static const int CIv[10] = {16, 8, 16, 16, 32, 32, 64, 64, 32, 16};
  static const int COv[10] = {8, 16, 16, 32, 32, 64, 64, 32, 16, 8};

  // ---- workspace: fp32 region first, then bf16 (ushort) region ----
  float* stats = (float*)d_ws;                       // 10 x NBUCKET x 128 floats
  float* yraw  = stats + 10 * NBUCKET * 128;         // max raw y = N1*16
  unsigned short* u = (unsigned short*)(yraw + (size_t)N1 * 16);

  unsigned short* wt[10];
  int wcum[11];
  wcum[0] = 0;
  for (int i = 0; i < 10; ++i) {
    wt[i] = u;
    int sz = 27 * CIv[i] * COv[i];
    u += sz;
    wcum[i + 1] = wcum[i] + sz;
  }
  unsigned short* featsb = u; u += (size_t)N0 * 16;
  unsigned short* c0f = u;    u += (size_t)N0 * 8;
  unsigned short* t1  = u;    u += (size_t)N1 * 16;
  unsigned short* c2f = u;    u += (size_t)N1 * 16;
  unsigned short* t2  = u;    u += (size_t)N2 * 32;
  unsigned short* c4f = u;    u += (size_t)N2 * 32;
  unsigned short* t3  = u;    u += (size_t)N3 * 64;
  unsigned short* t4  = u;    u += (size_t)N3 * 64;
  unsigned short* t5  = t2;   // reuse
  unsigned short* t6  = t1;   // reuse
  float* y9 = (float*)d_out;                         // conv9 raw staged in out region
  float* x0 = (float*)d_out + (size_t)N0 * 8;

  float* s[10];
  for (int i = 0; i < 10; ++i) s[i] = stats + i * NBUCKET * 128;

  // ---- prep: zero stats, feats->bf16, weights->bf16 transposed ----
  PrepArgs pa;
  for (int i = 0; i < 10; ++i) {
    pa.w[i] = w[i]; pa.wt[i] = wt[i];
    pa.ci[i] = CIv[i]; pa.co[i] = COv[i];
    pa.wcum[i] = wcum[i];
  }
  pa.wcum[10] = wcum[10];
  pa.feats = feats; pa.featsb = featsb;
  pa.nfeat4 = N0 * 16 / 4;
  pa.stats = stats;
  long prep_total = (10 * NBUCKET * 128 / 4) + pa.nfeat4 + wcum[10];
  prep_kernel<<<(int)((prep_total + 255) / 256), 256, 0, stream>>>(pa);

  auto bgrid = [](long nout, int co) { return (int)((nout * co / 4 + 255) / 256); };

  int xb0 = cdiv(N0, 64), xb1 = cdiv(N1, 64), xb2 = cdiv(N2, 64), xb3 = cdiv(N3, 64);

  // conv0: 16->8 @ N0
  conv_mfma<16, 8><<<dim3(xb0, 1), 256, 0, stream>>>(featsb, nbr0, wt[0], yraw, s[0], N0, xb0);
  bn_relu_bf16<8><<<bgrid(N0, 8), 256, 0, stream>>>(yraw, s[0], g[0], b[0], nullptr, c0f, N0, i0);

  // conv1: 8->16 down to N1
  conv_mfma<8, 16><<<dim3(xb1, 1), 256, 0, stream>>>(c0f, nbr_d01, wt[1], yraw, s[1], N1, xb1);
  bn_relu_bf16<16><<<bgrid(N1, 16), 256, 0, stream>>>(yraw, s[1], g[1], b[1], nullptr, t1, N1, i1);

  // conv2: 16->16 @ N1
  conv_mfma<16, 16><<<dim3(xb1, 1), 256, 0, stream>>>(t1, nbr1, wt[2], yraw, s[2], N1, xb1);
  bn_relu_bf16<16><<<bgrid(N1, 16), 256, 0, stream>>>(yraw, s[2], g[2], b[2], nullptr, c2f, N1, i1);

  // conv3: 16->32 down to N2
  conv_mfma<16, 32><<<dim3(xb2, 2), 256, 0, stream>>>(c2f, nbr_d12, wt[3], yraw, s[3], N2, xb2);
  bn_relu_bf16<32><<<bgrid(N2, 32), 256, 0, stream>>>(yraw, s[3], g[3], b[3], nullptr, t2, N2, i2);

  // conv4: 32->32 @ N2
  conv_mfma<32, 32><<<dim3(xb2, 2), 256, 0, stream>>>(t2, nbr2, wt[4], yraw, s[4], N2, xb2);
  bn_relu_bf16<32><<<bgrid(N2, 32), 256, 0, stream>>>(yraw, s[4], g[4], b[4], nullptr, c4f, N2, i2);

  // conv5: 32->64 down to N3
  conv_mfma<32, 64><<<dim3(xb3, 4), 256, 0, stream>>>(c4f, nbr_d23, wt[5], yraw, s[5], N3, xb3);
  bn_relu_bf16<64><<<bgrid(N3, 64), 256, 0, stream>>>(yraw, s[5], g[5], b[5], nullptr, t3, N3, i3);

  // conv6: 64->64 @ N3
  conv_mfma<64, 64><<<dim3(xb3, 4), 256, 0, stream>>>(t3, nbr3, wt[6], yraw, s[6], N3, xb3);
  bn_relu_bf16<64><<<bgrid(N3, 64), 256, 0, stream>>>(yraw, s[6], g[6], b[6], nullptr, t4, N3, i3);

  // conv7: 64->32 up to N2; x2 = c4f + relu(bn(y7))
  conv_mfma<64, 32><<<dim3(xb2, 2), 256, 0, stream>>>(t4, nbr_u32, wt[7], yraw, s[7], N2, xb2);
  bn_relu_bf16<32><<<bgrid(N2, 32), 256, 0, stream>>>(yraw, s[7], g[7], b[7], c4f, t5, N2, i2);

  // conv8: 32->16 up to N1; x1 = c2f + relu(bn(y8))
  conv_mfma<32, 16><<<dim3(xb1, 1), 256, 0, stream>>>(t5, nbr_u21, wt[8], yraw, s[8], N1, xb1);
  bn_relu_bf16<16><<<bgrid(N1, 16), 256, 0, stream>>>(yraw, s[8], g[8], b[8], c2f, t6, N1, i1);

  // conv9: 16->8 up to N0; raw y9 staged in out region
  conv_mfma<16, 8><<<dim3(xb0, 1), 256, 0, stream>>>(t6, nbr_u10, wt[9], y9, s[9], N0, xb0);

  // tail: x0 = c0f + relu(bn(y9)); out0 = x0 @ lin_w.T
  tail_kernel<<<cdiv(N0, 256), 256, 0, stream>>>(c0f, s[9], g[9], b[9], i0, lin_w, y9, x0, N0);
}